// Round 12
// baseline (414.741 us; speedup 1.0000x reference)
//
#include <hip/hip_runtime.h>
#include <hip/hip_bf16.h>

typedef __hip_bfloat16 bf16;
typedef __attribute__((ext_vector_type(8))) short s8v;   // 8 bf16 = 4 VGPRs
typedef __attribute__((ext_vector_type(4))) short s4v;   // 4 bf16 = 8 bytes
typedef __attribute__((ext_vector_type(4))) float f4v;

#define NPIX 4096
#define CDIM 256
#define MN_ELEMS (1 << 20)        // CDIM * NPIX
#define QKVSTR (320L * NPIX)      // qkv per-slot stride (elems)
#define QKTSTR (64L * NPIX)       // qkt per-slot stride (elems)
#define CNL ((long)CDIM * NPIX)

#if __has_builtin(__builtin_amdgcn_exp2f)
#define EXP2F(x) __builtin_amdgcn_exp2f(x)
#else
#define EXP2F(x) exp2f(x)
#endif

// ---- async global->LDS, 16B per lane (dest = wave-uniform base + lane*16) ---
typedef __attribute__((address_space(1))) const unsigned int g_u32;
typedef __attribute__((address_space(3))) unsigned int l_u32;
__device__ __forceinline__ void glds16(const void* g, void* l) {
  __builtin_amdgcn_global_load_lds((g_u32*)g, (l_u32*)l, 16, 0, 0);
}

// ---- 8-element loaders -> bf16x8 (s8v) --------------------------------------
__device__ inline s8v ld8(const bf16* p) { return *(const s8v*)p; }
__device__ inline s8v ld8(const float* p) {
  float4 f0 = *(const float4*)p;
  float4 f1 = *(const float4*)(p + 4);
  s8v r; bf16* e = (bf16*)&r;
  e[0] = __float2bfloat16(f0.x); e[1] = __float2bfloat16(f0.y);
  e[2] = __float2bfloat16(f0.z); e[3] = __float2bfloat16(f0.w);
  e[4] = __float2bfloat16(f1.x); e[5] = __float2bfloat16(f1.y);
  e[6] = __float2bfloat16(f1.z); e[7] = __float2bfloat16(f1.w);
  return r;
}

// ---------------------------------------------------------------------------
// Fused flash-style attention — 8 thin waves (512 thr), all LDS streams
// XOR-swizzled, counted-vmcnt pipeline (2 raw barriers/iter, K dbuf).
// (R10 kernel, verified: 65.6 us merged, 2.1M bank conflicts.)
// ---------------------------------------------------------------------------
template<int CB>
__global__ __launch_bounds__(512) void fattn_k(
    const bf16* __restrict__ qkt, const bf16* __restrict__ Vg,
    bf16* __restrict__ out)
{
  constexpr int SC = CB / 64;          // PV c-frags per wave
  __shared__ bf16 k_s[2][128 * 32];    // [buf][m 128][32] (swizzled rows)
  __shared__ bf16 v_s[4 * CB * 32];    // [kk][c CB][32] (swizzled rows)
  __shared__ bf16 p_s[4 * 64 * 32];    // [kk][n 64][32 m] (swizzled rows)
  __shared__ float sums[4 * 64];       // [m-quarter][n]

  const int tid = threadIdx.x;
  const int z = blockIdx.z;
  const int w = tid >> 6, lane = tid & 63;
  const int l15 = lane & 15, oct = lane >> 4;
  const int wr2 = w >> 2, wc2 = w & 3;     // S roles
  const int pc = w >> 1, pn = w & 1;       // PV roles
  const int n0 = blockIdx.x * 64, c0 = blockIdx.y * CB;
  const bf16* qk = qkt + (long)z * QKTSTR;
  const bf16* Vz = Vg + (long)z * QKVSTR;

  // staging source column pre-swizzle: row = tid>>2, quarter = tid&3
  const int t2 = tid >> 2;
  const int kq3 = ((tid & 3) ^ ((t2 >> 1) & 3)) * 8;      // for k_s / Q (row=t2)
  const int vrow = t2 & (CB - 1);                          // v_s row
  const int vq3 = ((tid & 3) ^ ((vrow >> 1) & 3)) * 8;     // for v_s

  auto stageK = [&](int m, int buf) {
    glds16(qk + (long)(m + t2) * 64 + 32 + kq3, &k_s[buf][tid * 8]);
  };
  auto stageV = [&](int m) {
    #pragma unroll
    for (int it = 0; it < CB / 32; ++it) {
      const int flat = it * 4096 + tid * 8;
      const int g = flat / (CB * 32);
      glds16(Vz + (long)(c0 + vrow) * 4096 + m + g * 32 + vq3, v_s + flat);
    }
  };

  // ---- prologue: stage Q (tid<256 -> p_s rows 0..63, swizzled), K(0), V(0) --
  if (tid < 256)
    glds16(qk + (long)(n0 + t2) * 64 + kq3, p_s + tid * 8);
  stageK(0, 0);
  stageV(0);
  __syncthreads();   // full drain once (prologue)

  s8v qf[2];
  #pragma unroll
  for (int st = 0; st < 2; ++st) {
    const int row = wr2 * 32 + st * 16 + l15;
    int byte = row * 64 + oct * 16;
    byte ^= ((row >> 1) & 3) << 4;
    qf[st] = *(const s8v*)((const char*)p_s + byte);
  }
  __syncthreads();   // all qf reads done before p_s is overwritten by P(0)

  f4v acc[SC][2];
  #pragma unroll
  for (int i = 0; i < SC; ++i)
    #pragma unroll
    for (int j = 0; j < 2; ++j) acc[i][j] = (f4v){0.f, 0.f, 0.f, 0.f};
  float rs[2] = {0.f, 0.f};

  for (int i = 0; i < 32; ++i) {
    const int cur = i & 1;
    if (i < 31) stageK((i + 1) * 128, cur ^ 1);   // in flight across this iter

    // ---- S^T phase: S[m][n] = k.q (q pre-scaled by log2e), exp2, pack -----
    s8v kf[2];
    #pragma unroll
    for (int nt = 0; nt < 2; ++nt) {
      const int row = wc2 * 32 + nt * 16 + l15;
      int byte = row * 64 + oct * 16;
      byte ^= ((row >> 1) & 3) << 4;
      kf[nt] = *(const s8v*)((const char*)&k_s[cur][0] + byte);
    }
    #pragma unroll
    for (int st = 0; st < 2; ++st) {
      const int n = wr2 * 32 + st * 16 + l15;          // P row (lane-fixed)
      const int sw = ((n >> 1) & 3) << 4;              // intra-row byte XOR
      f4v sa[2];
      __builtin_amdgcn_s_setprio(1);
      #pragma unroll
      for (int nt = 0; nt < 2; ++nt) {
        f4v zz = (f4v){0.f, 0.f, 0.f, 0.f};
        sa[nt] = __builtin_amdgcn_mfma_f32_16x16x32_bf16(kf[nt], qf[st], zz, 0, 0, 0);
      }
      __builtin_amdgcn_s_setprio(0);
      #pragma unroll
      for (int nt = 0; nt < 2; ++nt) {
        // m = wc2*32 + nt*16 + oct*4 + r  ->  kk = wc2
        int byte = wc2 * 4096 + n * 64 + nt * 32 + oct * 8;
        byte ^= sw;
        s4v pk; bf16* pe = (bf16*)&pk;
        float rsum = 0.f;
        #pragma unroll
        for (int r = 0; r < 4; ++r) {
          float e = EXP2F(sa[nt][r]);
          rsum += e;
          pe[r] = __float2bfloat16(e);
        }
        rs[st] += rsum;
        *(s4v*)((char*)p_s + byte) = pk;
      }
    }
    // ---- W1: V(i) landed + P visible; K(i+1) stays in flight --------------
    if (i < 31) asm volatile("s_waitcnt vmcnt(1) lgkmcnt(0)" ::: "memory");
    else        asm volatile("s_waitcnt vmcnt(0) lgkmcnt(0)" ::: "memory");
    __builtin_amdgcn_sched_barrier(0);
    __builtin_amdgcn_s_barrier();

    // ---- PV phase: acc[c][n] += V[c][m] * P[n][m], K=128 ------------------
    #pragma unroll
    for (int kk = 0; kk < 4; ++kk) {
      s8v vf[SC], pf[2];
      #pragma unroll
      for (int st = 0; st < SC; ++st) {
        const int row = pc * (CB / 4) + st * 16 + l15;
        int byte = kk * (CB * 64) + row * 64 + oct * 16;
        byte ^= ((row >> 1) & 3) << 4;
        vf[st] = *(const s8v*)((const char*)v_s + byte);
      }
      #pragma unroll
      for (int nt = 0; nt < 2; ++nt) {
        const int n = pn * 32 + nt * 16 + l15;
        int byte = kk * 4096 + n * 64 + oct * 16;
        byte ^= ((n >> 1) & 3) << 4;
        pf[nt] = *(const s8v*)((const char*)p_s + byte);
      }
      __builtin_amdgcn_s_setprio(1);
      #pragma unroll
      for (int st = 0; st < SC; ++st)
        #pragma unroll
        for (int nt = 0; nt < 2; ++nt)
          acc[st][nt] = __builtin_amdgcn_mfma_f32_16x16x32_bf16(vf[st], pf[nt], acc[st][nt], 0, 0, 0);
      __builtin_amdgcn_s_setprio(0);
    }
    // ---- W2: K(i+1) landed (cover = S+PV); then restage V -----------------
    asm volatile("s_waitcnt vmcnt(0)" ::: "memory");
    __builtin_amdgcn_sched_barrier(0);
    __builtin_amdgcn_s_barrier();

    if (i < 31) stageV((i + 1) * 128);   // drains at next iter's W1
  }

  // ---- row-sum: reduce over octs, combine 4 m-quarters via LDS ------------
  #pragma unroll
  for (int st = 0; st < 2; ++st) {
    rs[st] += __shfl_xor(rs[st], 16);
    rs[st] += __shfl_xor(rs[st], 32);
  }
  if (lane < 16) {
    #pragma unroll
    for (int st = 0; st < 2; ++st)
      sums[wc2 * 64 + wr2 * 32 + st * 16 + l15] = rs[st];
  }
  __syncthreads();

  float rinv[2];
  #pragma unroll
  for (int nt = 0; nt < 2; ++nt) {
    const int n = pn * 32 + nt * 16 + l15;
    rinv[nt] = 1.f / (sums[n] + sums[64 + n] + sums[128 + n] + sums[192 + n]);
  }
  bf16* op = out + (long)z * CNL;
  #pragma unroll
  for (int st = 0; st < SC; ++st) {
    const int gc = c0 + pc * (CB / 4) + st * 16 + oct * 4;
    #pragma unroll
    for (int nt = 0; nt < 2; ++nt) {
      const int gn = n0 + pn * 32 + nt * 16 + l15;
      #pragma unroll
      for (int r = 0; r < 4; ++r)
        op[(long)(gc + r) * NPIX + gn] = __float2bfloat16(acc[st][nt][r] * rinv[nt]);
    }
  }
}

// ---------------------------------------------------------------------------
// Fused direct 3x3 conv, cg-double-buffered: stage(cg+1) overlaps compute(cg).
// out[o][h*64+w] = bias[o] + sum_j sum_c W[o][j*256+c]*Xpad[c][h+dy-1][w+dx-1]
// LDS tile [row 3][wpos 66][c 64] per buffer (wpos stride 66 = conflict-free);
// 2 buffers = 52.3 KB.  One barrier per cg.  grid (64,2,2), 512 thr.
// ---------------------------------------------------------------------------
__global__ __launch_bounds__(512) void conv_k(
    const bf16* __restrict__ x, const bf16* __restrict__ wcvt,
    const float* __restrict__ bias, bf16* __restrict__ out)
{
  __shared__ bf16 lds[2][3 * 66 * 66];
  const int tid = threadIdx.x;
  const int h = blockIdx.x;
  const int o0 = blockIdx.y * 128;
  x   += (long)blockIdx.z * CDIM * NPIX;
  out += (long)blockIdx.z * CDIM * NPIX;

  const int w = tid >> 6, lane = tid & 63;
  const int l15 = lane & 15, oct = lane >> 4;
  const int w2 = tid & 31, chi = tid >> 5;

  // zero w-pad columns of both buffers once (never overwritten by staging)
  if (tid < 192) {
    int row = tid >> 6, c = tid & 63;
    #pragma unroll
    for (int b = 0; b < 2; ++b) {
      lds[b][(row * 66 + 0) * 66 + c] = __float2bfloat16(0.f);
      lds[b][(row * 66 + 65) * 66 + c] = __float2bfloat16(0.f);
    }
  }

  auto stage = [&](int cg, bf16* dst) {
    #pragma unroll
    for (int it = 0; it < 12; ++it) {
      int row = it >> 2, cgi = it & 3;
      int c = cgi * 16 + chi;
      int hh = h + row - 1;
      unsigned int pix = 0;
      if ((unsigned)hh < 64u)
        pix = *(const unsigned int*)(x + (long)(cg * 64 + c) * 4096 + hh * 64 + w2 * 2);
      const bf16* pp = (const bf16*)&pix;
      dst[(row * 66 + (w2 * 2 + 1)) * 66 + c] = pp[0];
      dst[(row * 66 + (w2 * 2 + 2)) * 66 + c] = pp[1];
    }
  };

  f4v acc[4];
  #pragma unroll
  for (int nf = 0; nf < 4; ++nf) acc[nf] = (f4v){0.f, 0.f, 0.f, 0.f};

  const long arow = (long)(o0 + w * 16 + l15) * 2304;

  stage(0, &lds[0][0]);
  __syncthreads();

  #pragma unroll
  for (int cg = 0; cg < 4; ++cg) {
    if (cg < 3) stage(cg + 1, &lds[(cg + 1) & 1][0]);   // overlaps compute(cg)
    const bf16* cl = &lds[cg & 1][0];
    #pragma unroll
    for (int j = 0; j < 9; ++j) {
      const int dy = j / 3, dx = j % 3;
      #pragma unroll
      for (int kc = 0; kc < 2; ++kc) {
        s8v af = *(const s8v*)(wcvt + arow + j * 256 + cg * 64 + kc * 32 + oct * 8);
        s8v bfv[4];
        #pragma unroll
        for (int nf = 0; nf < 4; ++nf)
          bfv[nf] = *(const s8v*)&cl[(dy * 66 + (nf * 16 + l15 + dx)) * 66 + kc * 32 + oct * 8];
        #pragma unroll
        for (int nf = 0; nf < 4; ++nf)
          acc[nf] = __builtin_amdgcn_mfma_f32_16x16x32_bf16(af, bfv[nf], acc[nf], 0, 0, 0);
      }
    }
    __syncthreads();   // staged(cg+1) visible; reads of lds[cg&1] done
  }

  // ---- epilogue: + bias, store ----
  #pragma unroll
  for (int nf = 0; nf < 4; ++nf) {
    const int gn = h * 64 + nf * 16 + l15;
    const int go = o0 + w * 16 + oct * 4;
    #pragma unroll
    for (int r = 0; r < 4; ++r)
      out[(long)(go + r) * NPIX + gn] = __float2bfloat16(acc[nf][r] + bias[go + r]);
  }
}

// ---- b_s swizzle helpers (proj/projc): byte-in-row ^= ((row>>3)&3)<<4 ------
// Writes (scalar b16, col-walk) spread 8-way->~2-way; reads (b128) keep the
// 40-elem-pad bank spread; XOR closed over {0,16,32,48} so stays in the 80B
// row and preserves 16B alignment.
__device__ __forceinline__ int bswz(int row, int byteInRow) {
  return row * 80 + (byteInRow ^ (((row >> 3) & 3) << 4));
}

// ---------------------------------------------------------------------------
// Projection GEMM (A+B stages). z = slot; stage = z>>1 selects param set;
// batch = z&1 offsets B. QKT=1: rows gm<64 -> qkt transposed, q rows scaled
// by log2(e).
// ---------------------------------------------------------------------------
template<int QKT, typename TBe>
__global__ __launch_bounds__(256) void proj_k(
    const float* __restrict__ A, const float* __restrict__ A2,
    const TBe* __restrict__ B1, const TBe* __restrict__ B2,
    const float* __restrict__ bias, const float* __restrict__ bias2,
    bf16* __restrict__ Cm, bf16* __restrict__ qkt,
    int M, int N, int K, long bbat, long cbat, int nchunk)
{
  __shared__ bf16 a_s[64][40];
  __shared__ bf16 b_s[64][40];
  const int tid = threadIdx.x;
  const int z = blockIdx.z, stage = z >> 1, bat = z & 1;
  const float* Au = stage ? A2 : A;
  const float* biasu = stage ? bias2 : bias;
  const TBe* Bm = (stage ? B2 : B1) + bat * bbat;
  Cm += z * cbat;
  if (QKT) qkt += z * QKTSTR;
  const int m0 = blockIdx.y * 64, n0 = blockIdx.x * 64;
  const int w = tid >> 6, lane = tid & 63;
  const int l15 = lane & 15, oct = lane >> 4;

  f4v acc[4];
  #pragma unroll
  for (int i = 0; i < 4; ++i) acc[i] = (f4v){0.f, 0.f, 0.f, 0.f};

  const int a_i0 = tid >> 2, a_i1 = (tid & 3) * 8;
  const int b_i0 = tid >> 3, b_i1 = (tid & 7) * 8;

  s8v pa, pb;
  auto ldA = [&](int kc, s8v& d) {
    if (m0 + a_i0 < M) d = ld8(Au + (long)(m0 + a_i0) * K + kc * 32 + a_i1);
    else d = (s8v){0,0,0,0,0,0,0,0};
  };
  auto ldB = [&](int kc, s8v& d) {
    d = ld8(Bm + (long)(kc * 32 + b_i0) * N + n0 + b_i1);
  };

  ldA(0, pa); ldB(0, pb);
  for (int kc = 0; kc < nchunk; ++kc) {
    *(s8v*)&a_s[a_i0][a_i1] = pa;
    {
      const bf16* e = (const bf16*)&pb;
      #pragma unroll
      for (int j = 0; j < 8; ++j)
        *(bf16*)((char*)b_s + bswz(b_i1 + j, 2 * b_i0)) = e[j];
    }
    __syncthreads();
    if (kc + 1 < nchunk) { ldA(kc + 1, pa); ldB(kc + 1, pb); }
    s8v af = *(const s8v*)&a_s[w * 16 + l15][oct * 8];
    #pragma unroll
    for (int nt = 0; nt < 4; ++nt) {
      s8v bfr = *(const s8v*)((const char*)b_s + bswz(nt * 16 + l15, oct * 16));
      acc[nt] = __builtin_amdgcn_mfma_f32_16x16x32_bf16(af, bfr, acc[nt], 0, 0, 0);
    }
    __syncthreads();
  }
  const int gm_base = m0 + w * 16 + oct * 4;
  #pragma unroll
  for (int nt = 0; nt < 4; ++nt) {
    const int gn = n0 + nt * 16 + l15;
    #pragma unroll
    for (int r = 0; r < 4; ++r) {
      int gm = gm_base + r;
      if (gm < M) {
        float vv = acc[nt][r] + biasu[gm];
        if (QKT && gm < 64) {
          float vv2 = (gm < 32) ? vv * 1.44269504f : vv;   // q *= log2(e)
          qkt[(long)gn * 64 + gm] = __float2bfloat16(vv2);
        } else {
          Cm[(long)gm * N + gn] = __float2bfloat16(vv);
        }
      }
    }
  }
}

// ---------------------------------------------------------------------------
// Stage-C projection, merged: grid (64 n, 5, 2 batch).
// y==0: qk-proj (wqk fp32, B=u2) -> qkt (transposed, q rows * log2e).
// y>=1: v-proj  (wv fp32, B=u3, m0=(y-1)*64) -> qkv V rows.
// ---------------------------------------------------------------------------
__global__ __launch_bounds__(256) void projc_k(
    const float* __restrict__ wqk, const float* __restrict__ bqk,
    const bf16* __restrict__ u2,
    const float* __restrict__ wv, const float* __restrict__ bvv,
    const bf16* __restrict__ u3,
    bf16* __restrict__ qkv, bf16* __restrict__ qkt)
{
  __shared__ bf16 a_s[64][40];
  __shared__ bf16 b_s[64][40];
  const int tid = threadIdx.x;
  const int bat = blockIdx.z;
  const int qkmode = (blockIdx.y == 0);
  const float* Au    = qkmode ? wqk : wv;
  const float* biasu = qkmode ? bqk : bvv;
  const bf16* Bm     = (qkmode ? u2 : u3) + (long)bat * CNL;
  const int M  = qkmode ? 64 : 256;
  const int m0 = qkmode ? 0 : (blockIdx.y - 1) * 64;
  const int n0 = blockIdx.x * 64;
  const int w = tid >> 6, lane = tid & 63;
  const int l15 = lane & 15, oct = lane >> 4;

  f4v acc[4];
  #pragma unroll
  for (int i = 0; i < 4; ++i) acc[i] = (f4v){0.f, 0.f, 0.f, 0.f};

  const int a_i0 = tid >> 2, a_i1 = (tid & 3) * 8;
  const int b_i0 = tid >> 3, b_i1 = (tid & 7) * 8;

  s8v pa, pb;
  auto ldA = [&](int kc, s8v& d) {
    if (m0 + a_i0 < M) d = ld8(Au + (long)(m0 + a_i0) * 256 + kc * 32 + a_i1);
    else d = (s8v){0,0,0,0,0,0,0,0};
  };
  auto ldB = [&](int kc, s8v& d) {
    d = ld8(Bm + (long)(kc * 32 + b_i0) * NPIX + n0 + b_i1);
  };

  ldA(0, pa); ldB(0, pb);
  for (int kc = 0; kc < 8; ++kc) {
    *(s8v*)&a_s[a_i0][a_i1] = pa;
    {
      const bf16* e = (const bf16*)&pb;
      #pragma unroll
      for (int j = 0; j < 8; ++j)
        *(bf16*)((char*)b_s + bswz(b_i1 + j, 2 * b_i0)) = e[j];
    }
    __syncthreads();
    if (kc + 1 < 8) { ldA(kc + 1, pa); ldB(kc + 1, pb); }
    s8v af = *(const s8v*)&a_s[w * 16 + l15][oct * 8];
    #pragma unroll
    for (int nt = 0; nt < 4; ++nt) {
      s8v bfr = *(const s8v*)((const char*)b_s + bswz(nt * 16 + l15, oct * 16));
      acc[nt] = __builtin_amdgcn_mfma_f32_16x16x32_bf16(af, bfr, acc[nt], 0, 0, 0);
    }
    __syncthreads();
  }
  const int gm_base = m0 + w * 16 + oct * 4;
  #pragma unroll
  for (int nt = 0; nt < 4; ++nt) {
    const int gn = n0 + nt * 16 + l15;
    #pragma unroll
    for (int r = 0; r < 4; ++r) {
      int gm = gm_base + r;
      if (gm < M) {
        float vv = acc[nt][r] + biasu[gm];
        if (qkmode) {
          float vv2 = (gm < 32) ? vv * 1.44269504f : vv;   // q *= log2(e)
          qkt[(long)bat * QKTSTR + (long)gn * 64 + gm] = __float2bfloat16(vv2);
        } else {
          qkv[64 * NPIX + (long)bat * QKVSTR + (long)gm * NPIX + gn] = __float2bfloat16(vv);
        }
      }
    }
  }
}

// ---------------------------------------------------------------------------
// Merged prep: cvtw2 (both convs) + cat x2 (320-row) + cat qk (64-row).
// ---------------------------------------------------------------------------
__global__ __launch_bounds__(256) void prep_k(
    const float* __restrict__ cw1, const float* __restrict__ cw2,
    bf16* __restrict__ o1, bf16* __restrict__ o2,
    const float* __restrict__ q1, const float* __restrict__ qb1,
    const float* __restrict__ k1, const float* __restrict__ kb1,
    const float* __restrict__ v1, const float* __restrict__ vb1,
    float* __restrict__ wcat1, float* __restrict__ bcat1,
    const float* __restrict__ q2, const float* __restrict__ qb2,
    const float* __restrict__ k2, const float* __restrict__ kb2,
    const float* __restrict__ v2, const float* __restrict__ vb2,
    float* __restrict__ wcat2, float* __restrict__ bcat2,
    const float* __restrict__ qq, const float* __restrict__ qqb,
    const float* __restrict__ kk, const float* __restrict__ kkb,
    float* __restrict__ wqk, float* __restrict__ bqk)
{
  long idx = (long)blockIdx.x * 256 + threadIdx.x;
  if (idx < 1179648) {
    const float* in = (idx < 589824) ? cw1 : cw2;
    bf16* out = (idx < 589824) ? o1 : o2;
    long i = (idx < 589824) ? idx : idx - 589824;
    int o = (int)(i / 2304), r = (int)(i % 2304);
    int j = r >> 8, c = r & 255;
    out[i] = __float2bfloat16(in[(o * 256 + c) * 9 + j]);
    return;
  }
  idx -= 1179648;
  const float *wq, *bq, *wk, *bk, *wv, *bv;
  float *wcat, *bcat; int M;
  if (idx < 82240) {
    wq = q1; bq = qb1; wk = k1; bk = kb1; wv = v1; bv = vb1;
    wcat = wcat1; bcat = bcat1; M = 320;
  } else if (idx < 164480) {
    idx -= 82240;
    wq = q2; bq = qb2; wk = k2; bk = kb2; wv = v2; bv = vb2;
    wcat = wcat2; bcat = bcat2; M = 320;
  } else if (idx < 180928) {
    idx -= 164480;
    wq = qq; bq = qqb; wk = kk; bk = kkb; wv = nullptr; bv = nullptr;
    wcat = wqk; bcat = bqk; M = 64;
  } else return;
  int total = M << 8;
  if (idx < total) {
    int r = (int)(idx >> 8), c = (int)(idx & 255);
    float v;
    if (r < 32) v = wq[r * 256 + c];
    else if (r < 64) v = wk[(r - 32) * 256 + c];
    else v = wv[(r - 64) * 256 + c];
    wcat[idx] = v;
  } else if (idx < total + M) {
    int r = (int)(idx - total);
    bcat[r] = (r < 32) ? bq[r] : (r < 64) ? bk[r - 32] : bv[r - 64];
  }
}

// ---- 16-elem row load/store helpers ----------------------------------------
__device__ inline void ld16(const bf16* p, float* v) {
  s8v r0 = *(const s8v*)p, r1 = *(const s8v*)(p + 8);
  const bf16* e0 = (const bf16*)&r0; const bf16* e1 = (const bf16*)&r1;
  #pragma unroll
  for (int j = 0; j < 8; ++j) { v[j] = __bfloat162float(e0[j]); v[8 + j] = __bfloat162float(e1[j]); }
}
__device__ inline void ld16(const float* p, float* v) {
  #pragma unroll
  for (int q = 0; q < 4; ++q) {
    float4 f = *(const float4*)(p + q * 4);
    v[q * 4 + 0] = f.x; v[q * 4 + 1] = f.y; v[q * 4 + 2] = f.z; v[q * 4 + 3] = f.w;
  }
}
__device__ inline void st16(bf16* p, const float* v) {
  s8v o0, o1v; bf16* f0 = (bf16*)&o0; bf16* f1 = (bf16*)&o1v;
  #pragma unroll
  for (int j = 0; j < 8; ++j) { f0[j] = __float2bfloat16(v[j]); f1[j] = __float2bfloat16(v[8 + j]); }
  *(s8v*)p = o0; *(s8v*)(p + 8) = o1v;
}
__device__ inline void st16(float* p, const float* v) {
  #pragma unroll
  for (int q = 0; q < 4; ++q) {
    float4 f; f.x = v[q * 4 + 0]; f.y = v[q * 4 + 1]; f.z = v[q * 4 + 2]; f.w = v[q * 4 + 3];
    *(float4*)(p + q * 4) = f;
  }
}

// ---- fused InstanceNorm: out = inorm(g*a + b) per row of 4096 --------------
template<typename TAe, typename TBe, typename TOe, int G>
__global__ __launch_bounds__(256) void inorm_k(
    const TAe* __restrict__ a, const TBe* __restrict__ b,
    const float* __restrict__ g, TOe* __restrict__ out)
{
  __shared__ float red[8];
  const int tid = threadIdx.x;
  const long base = (long)blockIdx.x * NPIX + tid * 16;
  float gv = G ? *g : 1.f;
  float va[16], vbv[16], v[16];
  ld16(a + base, va);
  ld16(b + base, vbv);
  #pragma unroll
  for (int j = 0; j < 16; ++j) v[j] = gv * va[j] + vbv[j];
  float sum = 0.f, sq = 0.f;
  #pragma unroll
  for (int j = 0; j < 16; ++j) { sum += v[j]; sq += v[j] * v[j]; }
  #pragma unroll
  for (int s = 32; s; s >>= 1) { sum += __shfl_xor(sum, s); sq += __shfl_xor(sq, s); }
  if ((tid & 63) == 0) { red[tid >> 6] = sum; red[4 + (tid >> 6)] = sq; }
  __syncthreads();
  sum = red[0] + red[1] + red[2] + red[3];
  sq  = red[4] + red[5] + red[6] + red[7];
  float mean = sum * (1.f / NPIX);
  float var  = fmaxf(sq * (1.f / NPIX) - mean * mean, 0.f);
  float rstd = rsqrtf(var + 1e-5f);
  float o[16];
  #pragma unroll
  for (int j = 0; j < 16; ++j) o[j] = (v[j] - mean) * rstd;
  st16(out + base, o);
}

// ---- two independent InstanceNorms in one launch (both bf16+float, G=1) ----
__global__ __launch_bounds__(256) void inorm2_k(
    const bf16* __restrict__ a0, const float* __restrict__ b0,
    const float* __restrict__ g0, bf16* __restrict__ o0,
    const bf16* __restrict__ a1, const float* __restrict__ b1,
    const float* __restrict__ g1, bf16* __restrict__ o1)
{
  __shared__ float red[8];
  const int tid = threadIdx.x;
  const int sel = blockIdx.x >> 9;
  const int row = blockIdx.x & 511;
  const bf16* a = sel ? a1 : a0;
  const float* b = sel ? b1 : b0;
  const float* g = sel ? g1 : g0;
  bf16* out = sel ? o1 : o0;
  const long base = (long)row * NPIX + tid * 16;
  float gv = *g;
  float va[16], vbv[16], v[16];
  ld16(a + base, va);
  ld16(b + base, vbv);
  #pragma unroll
  for (int j = 0; j < 16; ++j) v[j] = gv * va[j] + vbv[j];
  float sum = 0.f, sq = 0.f;
  #pragma unroll
  for (int j = 0; j < 16; ++j) { sum += v[j]; sq += v[j] * v[j]; }
  #pragma unroll
  for (int s = 32; s; s >>= 1) { sum += __shfl_xor(sum, s); sq += __shfl_xor(sq, s); }
  if ((tid & 63) == 0) { red[tid >> 6] = sum; red[4 + (tid >> 6)] = sq; }
  __syncthreads();
  sum = red[0] + red[1] + red[2] + red[3];
  sq  = red[4] + red[5] + red[6] + red[7];
  float mean = sum * (1.f / NPIX);
  float var  = fmaxf(sq * (1.f / NPIX) - mean * mean, 0.f);
  float rstd = rsqrtf(var + 1e-5f);
  float o[16];
  #pragma unroll
  for (int j = 0; j < 16; ++j) o[j] = (v[j] - mean) * rstd;
  st16(out + base, o);
}

// ---- fused dependent pair: u4 = inorm(inorm(g*t0 + y) + u3) ----------------
__global__ __launch_bounds__(256) void inorm_pair_k(
    const bf16* __restrict__ t0, const float* __restrict__ y,
    const float* __restrict__ g, const bf16* __restrict__ u3,
    bf16* __restrict__ u4)
{
  __shared__ float red[16];
  const int tid = threadIdx.x;
  const long base = (long)blockIdx.x * NPIX + tid * 16;
  float gv = *g;
  float va[16], vbv[16], v[16];
  ld16(t0 + base, va);
  ld16(y + base, vbv);
  #pragma unroll
  for (int j = 0; j < 16; ++j) v[j] = gv * va[j] + vbv[j];
  float sum = 0.f, sq = 0.f;
  #pragma unroll
  for (int j = 0; j < 16; ++j) { sum += v[j]; sq += v[j] * v[j]; }
  #pragma unroll
  for (int s = 32; s; s >>= 1) { sum += __shfl_xor(sum, s); sq += __shfl_xor(sq, s); }
  if ((tid & 63) == 0) { red[tid >> 6] = sum; red[4 + (tid >> 6)] = sq; }
  __syncthreads();
  sum = red[0] + red[1] + red[2] + red[3];
  sq  = red[4] + red[5] + red[6] + red[7];
  float mean = sum * (1.f / NPIX);
  float var  = fmaxf(sq * (1.f / NPIX) - mean * mean, 0.f);
  float rstd = rsqrtf(var + 1e-5f);
  // second stage: w = o1 + u3, stats again
  float vu[16];
  ld16(u3 + base, vu);
  #pragma unroll
  for (int j = 0; j < 16; ++j) v[j] = (v[j] - mean) * rstd + vu[j];
  sum = 0.f; sq = 0.f;
  #pragma unroll
  for (int j = 0; j < 16; ++j) { sum += v[j]; sq += v[j] * v[j]; }
  #pragma unroll
  for (int s = 32; s; s >>= 1) { sum += __shfl_xor(sum, s); sq += __shfl_xor(sq, s); }
  if ((tid & 63) == 0) { red[8 + (tid >> 6)] = sum; red[12 + (tid >> 6)] = sq; }
  __syncthreads();
  sum = red[8] + red[9] + red[10] + red[11];
  sq  = red[12] + red[13] + red[14] + red[15];
  mean = sum * (1.f / NPIX);
  var  = fmaxf(sq * (1.f / NPIX) - mean * mean, 0.f);
  rstd = rsqrtf(var + 1e-5f);
  float o[16];
  #pragma unroll
  for (int j = 0; j < 16; ++j) o[j] = (v[j] - mean) * rstd;
  st16(u4 + base, o);
}

// ---- host-side helpers ------------------------------------------------------
static const long CN = CNL;

// fused flash attention: CB picked so both launches are 512 blocks (2/CU).
static void attn_core(int nb, bf16* qkv, bf16* qkt, bf16* t0, hipStream_t stream)
{
  if (nb == 4)
    fattn_k<128><<<dim3(64, 2, 4), dim3(512), 0, stream>>>(qkt, qkv + 64 * NPIX, t0);
  else
    fattn_k<64><<<dim3(64, 4, 2), dim3(512), 0, stream>>>(qkt, qkv + 64 * NPIX, t0);
}

static void run_conv(const bf16* src, const bf16* wcvt, const float* cb,
                     bf16* dst, hipStream_t stream)
{
  conv_k<<<dim3(64, 2, 2), dim3(512), 0, stream>>>(src, wcvt, cb, dst);
}

// ---------------------------------------------------------------------------
extern "C" void kernel_launch(void* const* d_in, const int* in_sizes, int n_in,
                              void* d_out, int out_size, void* d_ws, size_t ws_size,
                              hipStream_t stream)
{
  (void)in_sizes; (void)n_in; (void)out_size; (void)ws_size;
  const float* x = (const float*)d_in[0];
  const float* y = (const float*)d_in[1];
  auto W = [&](int i) { return (const float*)d_in[i]; };

  char* wp = (char*)d_ws;
  auto take = [&](size_t nbytes) { char* p = wp; wp += (nbytes + 255) & ~(size_t)255; return p; };
  bf16*  qkv   = (bf16*)take((size_t)4 * QKVSTR * 2);
  bf16*  qkt   = (bf16*)take((size_t)4 * QKTSTR * 2);
  bf16*  t0    = (bf16*)take((size_t)4 * CN * 2);
  bf16*  u1    = (bf16*)take(2 * CN * 2);
  bf16*  u2    = (bf16*)take(2 * CN * 2);
  bf16*  u3    = (bf16*)take(2 * CN * 2);
  bf16*  u4    = (bf16*)take(2 * CN * 2);
  bf16*  wcvt1 = (bf16*)take((size_t)589824 * 2);
  bf16*  wcvt2 = (bf16*)take((size_t)589824 * 2);
  float* wcat1 = (float*)take((size_t)81920 * 4);
  float* bcat1 = (float*)take(320 * 4);
  float* wcat2 = (float*)take((size_t)81920 * 4);
  float* bcat2 = (float*)take(320 * 4);
  float* wqk   = (float*)take((size_t)16384 * 4);
  float* bqk   = (float*)take(64 * 4);
  bf16*  cvout = qkv;                                         // conv out (aliased)

  dim3 TB(256);

  // ---- prep: all weight concat/convert in one launch ----
  prep_k<<<dim3(5315), TB, 0, stream>>>(
      W(23), W(25), wcvt1, wcvt2,
      W(2), W(3), W(4), W(5), W(6), W(7), wcat1, bcat1,
      W(9), W(10), W(11), W(12), W(13), W(14), wcat2, bcat2,
      W(16), W(17), W(18), W(19), wqk, bqk);

  // ---- stages A+B attention together: z = stage*2 + batch ----
  proj_k<1,float><<<dim3(64,5,4), TB, 0, stream>>>(
      wcat1, wcat2, x, y, bcat1, bcat2, qkv, qkt, 320, NPIX, 256, CN, QKVSTR, 8);
  attn_core(4, qkv, qkt, t0, stream);

  // ---- out_1 / out_3 inorms (merged) ----
  inorm2_k<<<dim3(1024), TB, 0, stream>>>(t0, x, W(8), u1,
                                          t0 + 2 * CN, y, W(15), u3);

  // ---- conv1 -> out_2 ----
  run_conv(u1, wcvt1, W(24), cvout, stream);
  inorm_k<bf16,bf16,bf16,0><<<dim3(512), TB, 0, stream>>>(u1, cvout, nullptr, u2);

  // ---- stage C: merged projection (qk from out_2, v from out_3) ----
  projc_k<<<dim3(64, 5, 2), TB, 0, stream>>>(
      wqk, bqk, u2, W(20), W(21), u3, qkv, qkt);
  attn_core(2, qkv, qkt, t0, stream);
  // fused: u4 = inorm(inorm(g*t0 + y) + u3)
  inorm_pair_k<<<dim3(512), TB, 0, stream>>>(t0, y, W(22), u3, u4);
  run_conv(u4, wcvt2, W(26), cvout, stream);
  inorm_k<bf16,bf16,float,0><<<dim3(512), TB, 0, stream>>>(u4, cvout, nullptr, (float*)d_out);
}

// Round 13
// 347.340 us; speedup vs baseline: 1.1940x; 1.1940x over previous
//
#include <hip/hip_runtime.h>
#include <hip/hip_bf16.h>

typedef __hip_bfloat16 bf16;
typedef __attribute__((ext_vector_type(8))) short s8v;   // 8 bf16 = 4 VGPRs
typedef __attribute__((ext_vector_type(4))) short s4v;   // 4 bf16 = 8 bytes
typedef __attribute__((ext_vector_type(4))) float f4v;

#define NPIX 4096
#define CDIM 256
#define MN_ELEMS (1 << 20)        // CDIM * NPIX
#define QKVSTR (320L * NPIX)      // qkv per-slot stride (elems)
#define QKTSTR (64L * NPIX)       // qkt per-slot stride (elems)
#define CNL ((long)CDIM * NPIX)

#if __has_builtin(__builtin_amdgcn_exp2f)
#define EXP2F(x) __builtin_amdgcn_exp2f(x)
#else
#define EXP2F(x) exp2f(x)
#endif

// ---- async global->LDS, 16B per lane (dest = wave-uniform base + lane*16) ---
typedef __attribute__((address_space(1))) const unsigned int g_u32;
typedef __attribute__((address_space(3))) unsigned int l_u32;
__device__ __forceinline__ void glds16(const void* g, void* l) {
  __builtin_amdgcn_global_load_lds((g_u32*)g, (l_u32*)l, 16, 0, 0);
}

// ---- 8-element loaders -> bf16x8 (s8v) --------------------------------------
__device__ inline s8v ld8(const bf16* p) { return *(const s8v*)p; }
__device__ inline s8v ld8(const float* p) {
  float4 f0 = *(const float4*)p;
  float4 f1 = *(const float4*)(p + 4);
  s8v r; bf16* e = (bf16*)&r;
  e[0] = __float2bfloat16(f0.x); e[1] = __float2bfloat16(f0.y);
  e[2] = __float2bfloat16(f0.z); e[3] = __float2bfloat16(f0.w);
  e[4] = __float2bfloat16(f1.x); e[5] = __float2bfloat16(f1.y);
  e[6] = __float2bfloat16(f1.z); e[7] = __float2bfloat16(f1.w);
  return r;
}

// ---------------------------------------------------------------------------
// Fused flash-style attention — 8 thin waves (512 thr), all LDS streams
// XOR-swizzled, counted-vmcnt pipeline (2 raw barriers/iter, K dbuf).
// (R10/R11 kernel, verified: 65.6 us merged, 2.1M bank conflicts.)
// ---------------------------------------------------------------------------
template<int CB>
__global__ __launch_bounds__(512) void fattn_k(
    const bf16* __restrict__ qkt, const bf16* __restrict__ Vg,
    bf16* __restrict__ out)
{
  constexpr int SC = CB / 64;          // PV c-frags per wave
  __shared__ bf16 k_s[2][128 * 32];    // [buf][m 128][32] (swizzled rows)
  __shared__ bf16 v_s[4 * CB * 32];    // [kk][c CB][32] (swizzled rows)
  __shared__ bf16 p_s[4 * 64 * 32];    // [kk][n 64][32 m] (swizzled rows)
  __shared__ float sums[4 * 64];       // [m-quarter][n]

  const int tid = threadIdx.x;
  const int z = blockIdx.z;
  const int w = tid >> 6, lane = tid & 63;
  const int l15 = lane & 15, oct = lane >> 4;
  const int wr2 = w >> 2, wc2 = w & 3;     // S roles
  const int pc = w >> 1, pn = w & 1;       // PV roles
  const int n0 = blockIdx.x * 64, c0 = blockIdx.y * CB;
  const bf16* qk = qkt + (long)z * QKTSTR;
  const bf16* Vz = Vg + (long)z * QKVSTR;

  // staging source column pre-swizzle: row = tid>>2, quarter = tid&3
  const int t2 = tid >> 2;
  const int kq3 = ((tid & 3) ^ ((t2 >> 1) & 3)) * 8;      // for k_s / Q (row=t2)
  const int vrow = t2 & (CB - 1);                          // v_s row
  const int vq3 = ((tid & 3) ^ ((vrow >> 1) & 3)) * 8;     // for v_s

  auto stageK = [&](int m, int buf) {
    glds16(qk + (long)(m + t2) * 64 + 32 + kq3, &k_s[buf][tid * 8]);
  };
  auto stageV = [&](int m) {
    #pragma unroll
    for (int it = 0; it < CB / 32; ++it) {
      const int flat = it * 4096 + tid * 8;
      const int g = flat / (CB * 32);
      glds16(Vz + (long)(c0 + vrow) * 4096 + m + g * 32 + vq3, v_s + flat);
    }
  };

  // ---- prologue: stage Q (tid<256 -> p_s rows 0..63, swizzled), K(0), V(0) --
  if (tid < 256)
    glds16(qk + (long)(n0 + t2) * 64 + kq3, p_s + tid * 8);
  stageK(0, 0);
  stageV(0);
  __syncthreads();   // full drain once (prologue)

  s8v qf[2];
  #pragma unroll
  for (int st = 0; st < 2; ++st) {
    const int row = wr2 * 32 + st * 16 + l15;
    int byte = row * 64 + oct * 16;
    byte ^= ((row >> 1) & 3) << 4;
    qf[st] = *(const s8v*)((const char*)p_s + byte);
  }
  __syncthreads();   // all qf reads done before p_s is overwritten by P(0)

  f4v acc[SC][2];
  #pragma unroll
  for (int i = 0; i < SC; ++i)
    #pragma unroll
    for (int j = 0; j < 2; ++j) acc[i][j] = (f4v){0.f, 0.f, 0.f, 0.f};
  float rs[2] = {0.f, 0.f};

  for (int i = 0; i < 32; ++i) {
    const int cur = i & 1;
    if (i < 31) stageK((i + 1) * 128, cur ^ 1);   // in flight across this iter

    // ---- S^T phase: S[m][n] = k.q (q pre-scaled by log2e), exp2, pack -----
    s8v kf[2];
    #pragma unroll
    for (int nt = 0; nt < 2; ++nt) {
      const int row = wc2 * 32 + nt * 16 + l15;
      int byte = row * 64 + oct * 16;
      byte ^= ((row >> 1) & 3) << 4;
      kf[nt] = *(const s8v*)((const char*)&k_s[cur][0] + byte);
    }
    #pragma unroll
    for (int st = 0; st < 2; ++st) {
      const int n = wr2 * 32 + st * 16 + l15;          // P row (lane-fixed)
      const int sw = ((n >> 1) & 3) << 4;              // intra-row byte XOR
      f4v sa[2];
      __builtin_amdgcn_s_setprio(1);
      #pragma unroll
      for (int nt = 0; nt < 2; ++nt) {
        f4v zz = (f4v){0.f, 0.f, 0.f, 0.f};
        sa[nt] = __builtin_amdgcn_mfma_f32_16x16x32_bf16(kf[nt], qf[st], zz, 0, 0, 0);
      }
      __builtin_amdgcn_s_setprio(0);
      #pragma unroll
      for (int nt = 0; nt < 2; ++nt) {
        // m = wc2*32 + nt*16 + oct*4 + r  ->  kk = wc2
        int byte = wc2 * 4096 + n * 64 + nt * 32 + oct * 8;
        byte ^= sw;
        s4v pk; bf16* pe = (bf16*)&pk;
        float rsum = 0.f;
        #pragma unroll
        for (int r = 0; r < 4; ++r) {
          float e = EXP2F(sa[nt][r]);
          rsum += e;
          pe[r] = __float2bfloat16(e);
        }
        rs[st] += rsum;
        *(s4v*)((char*)p_s + byte) = pk;
      }
    }
    // ---- W1: V(i) landed + P visible; K(i+1) stays in flight --------------
    if (i < 31) asm volatile("s_waitcnt vmcnt(1) lgkmcnt(0)" ::: "memory");
    else        asm volatile("s_waitcnt vmcnt(0) lgkmcnt(0)" ::: "memory");
    __builtin_amdgcn_sched_barrier(0);
    __builtin_amdgcn_s_barrier();

    // ---- PV phase: acc[c][n] += V[c][m] * P[n][m], K=128 ------------------
    #pragma unroll
    for (int kk = 0; kk < 4; ++kk) {
      s8v vf[SC], pf[2];
      #pragma unroll
      for (int st = 0; st < SC; ++st) {
        const int row = pc * (CB / 4) + st * 16 + l15;
        int byte = kk * (CB * 64) + row * 64 + oct * 16;
        byte ^= ((row >> 1) & 3) << 4;
        vf[st] = *(const s8v*)((const char*)v_s + byte);
      }
      #pragma unroll
      for (int nt = 0; nt < 2; ++nt) {
        const int n = pn * 32 + nt * 16 + l15;
        int byte = kk * 4096 + n * 64 + oct * 16;
        byte ^= ((n >> 1) & 3) << 4;
        pf[nt] = *(const s8v*)((const char*)p_s + byte);
      }
      __builtin_amdgcn_s_setprio(1);
      #pragma unroll
      for (int st = 0; st < SC; ++st)
        #pragma unroll
        for (int nt = 0; nt < 2; ++nt)
          acc[st][nt] = __builtin_amdgcn_mfma_f32_16x16x32_bf16(vf[st], pf[nt], acc[st][nt], 0, 0, 0);
      __builtin_amdgcn_s_setprio(0);
    }
    // ---- W2: K(i+1) landed (cover = S+PV); then restage V -----------------
    asm volatile("s_waitcnt vmcnt(0)" ::: "memory");
    __builtin_amdgcn_sched_barrier(0);
    __builtin_amdgcn_s_barrier();

    if (i < 31) stageV((i + 1) * 128);   // drains at next iter's W1
  }

  // ---- row-sum: reduce over octs, combine 4 m-quarters via LDS ------------
  #pragma unroll
  for (int st = 0; st < 2; ++st) {
    rs[st] += __shfl_xor(rs[st], 16);
    rs[st] += __shfl_xor(rs[st], 32);
  }
  if (lane < 16) {
    #pragma unroll
    for (int st = 0; st < 2; ++st)
      sums[wc2 * 64 + wr2 * 32 + st * 16 + l15] = rs[st];
  }
  __syncthreads();

  float rinv[2];
  #pragma unroll
  for (int nt = 0; nt < 2; ++nt) {
    const int n = pn * 32 + nt * 16 + l15;
    rinv[nt] = 1.f / (sums[n] + sums[64 + n] + sums[128 + n] + sums[192 + n]);
  }
  bf16* op = out + (long)z * CNL;
  #pragma unroll
  for (int st = 0; st < SC; ++st) {
    const int gc = c0 + pc * (CB / 4) + st * 16 + oct * 4;
    #pragma unroll
    for (int nt = 0; nt < 2; ++nt) {
      const int gn = n0 + pn * 32 + nt * 16 + l15;
      #pragma unroll
      for (int r = 0; r < 4; ++r)
        op[(long)(gc + r) * NPIX + gn] = __float2bfloat16(acc[st][nt][r] * rinv[nt]);
    }
  }
}

// ---------------------------------------------------------------------------
// Fused direct 3x3 conv — single-buffer (R11 body), 256 threads, o-split 64:
// grid (64 h, 4 o, 2 batch) = 512 blocks -> 2 blocks/CU so one block's stage
// overlaps the other's MFMA (the 1-block/CU version measured 78 us at
// MfmaUtil 4.5% -- pure latency-bound lockstep).
// LDS tile [row 3][wpos 66][c 64] (wpos stride 66 = conflict-free), 26.4 KB.
// Staging = im2colT2's proven 24-iter pattern (4B/lane).
// ---------------------------------------------------------------------------
__global__ __launch_bounds__(256) void conv_k(
    const bf16* __restrict__ x, const bf16* __restrict__ wcvt,
    const float* __restrict__ bias, bf16* __restrict__ out)
{
  __shared__ bf16 lds[3 * 66 * 66];   // [row][wpos][c(64, 2 pad)]
  const int tid = threadIdx.x;
  const int h = blockIdx.x;
  const int o0 = blockIdx.y * 64;
  x   += (long)blockIdx.z * CDIM * NPIX;
  out += (long)blockIdx.z * CDIM * NPIX;

  const int w = tid >> 6, lane = tid & 63;
  const int l15 = lane & 15, oct = lane >> 4;
  const int w2 = tid & 31, chi = tid >> 5;   // staging: pixel-pair, c-sub

  // zero the w-pad columns once (wpos 0 and 65; never overwritten by staging)
  if (tid < 192) {
    int row = tid >> 6, c = tid & 63;
    lds[(row * 66 + 0) * 66 + c] = __float2bfloat16(0.f);
    lds[(row * 66 + 65) * 66 + c] = __float2bfloat16(0.f);
  }

  f4v acc[4];
  #pragma unroll
  for (int nf = 0; nf < 4; ++nf) acc[nf] = (f4v){0.f, 0.f, 0.f, 0.f};

  const long arow = (long)(o0 + w * 16 + l15) * 2304;

  for (int cg = 0; cg < 4; ++cg) {
    __syncthreads();   // pad/compute(cg-1) reads done before overwrite
    #pragma unroll
    for (int it = 0; it < 24; ++it) {
      int row = it >> 3, cg8 = it & 7;
      int c = cg8 * 8 + chi;
      int hh = h + row - 1;
      unsigned int pix = 0;
      if ((unsigned)hh < 64u)
        pix = *(const unsigned int*)(x + (long)(cg * 64 + c) * 4096 + hh * 64 + w2 * 2);
      const bf16* pp = (const bf16*)&pix;
      lds[(row * 66 + (w2 * 2 + 1)) * 66 + c] = pp[0];
      lds[(row * 66 + (w2 * 2 + 2)) * 66 + c] = pp[1];
    }
    __syncthreads();   // tile(cg) ready

    #pragma unroll
    for (int j = 0; j < 9; ++j) {
      const int dy = j / 3, dx = j % 3;
      #pragma unroll
      for (int kc = 0; kc < 2; ++kc) {
        s8v af = *(const s8v*)(wcvt + arow + j * 256 + cg * 64 + kc * 32 + oct * 8);
        s8v bfv[4];
        #pragma unroll
        for (int nf = 0; nf < 4; ++nf)
          bfv[nf] = *(const s8v*)&lds[(dy * 66 + (nf * 16 + l15 + dx)) * 66 + kc * 32 + oct * 8];
        #pragma unroll
        for (int nf = 0; nf < 4; ++nf)
          acc[nf] = __builtin_amdgcn_mfma_f32_16x16x32_bf16(af, bfv[nf], acc[nf], 0, 0, 0);
      }
    }
  }

  // ---- epilogue: + bias, store ----
  #pragma unroll
  for (int nf = 0; nf < 4; ++nf) {
    const int gn = h * 64 + nf * 16 + l15;
    const int go = o0 + w * 16 + oct * 4;
    #pragma unroll
    for (int r = 0; r < 4; ++r)
      out[(long)(go + r) * NPIX + gn] = __float2bfloat16(acc[nf][r] + bias[go + r]);
  }
}

// ---------------------------------------------------------------------------
// Projection GEMM (A+B stages). z = slot; stage = z>>1 selects param set;
// batch = z&1 offsets B. QKT=1: rows gm<64 -> qkt transposed, q rows scaled
// by log2(e).  (R11 body, unswizzled b_s.)
// ---------------------------------------------------------------------------
template<int QKT, typename TBe>
__global__ __launch_bounds__(256) void proj_k(
    const float* __restrict__ A, const float* __restrict__ A2,
    const TBe* __restrict__ B1, const TBe* __restrict__ B2,
    const float* __restrict__ bias, const float* __restrict__ bias2,
    bf16* __restrict__ Cm, bf16* __restrict__ qkt,
    int M, int N, int K, long bbat, long cbat, int nchunk)
{
  __shared__ bf16 a_s[64][40];
  __shared__ bf16 b_s[64][40];
  const int tid = threadIdx.x;
  const int z = blockIdx.z, stage = z >> 1, bat = z & 1;
  const float* Au = stage ? A2 : A;
  const float* biasu = stage ? bias2 : bias;
  const TBe* Bm = (stage ? B2 : B1) + bat * bbat;
  Cm += z * cbat;
  if (QKT) qkt += z * QKTSTR;
  const int m0 = blockIdx.y * 64, n0 = blockIdx.x * 64;
  const int w = tid >> 6, lane = tid & 63;
  const int l15 = lane & 15, oct = lane >> 4;

  f4v acc[4];
  #pragma unroll
  for (int i = 0; i < 4; ++i) acc[i] = (f4v){0.f, 0.f, 0.f, 0.f};

  const int a_i0 = tid >> 2, a_i1 = (tid & 3) * 8;
  const int b_i0 = tid >> 3, b_i1 = (tid & 7) * 8;

  s8v pa, pb;
  auto ldA = [&](int kc, s8v& d) {
    if (m0 + a_i0 < M) d = ld8(Au + (long)(m0 + a_i0) * K + kc * 32 + a_i1);
    else d = (s8v){0,0,0,0,0,0,0,0};
  };
  auto ldB = [&](int kc, s8v& d) {
    d = ld8(Bm + (long)(kc * 32 + b_i0) * N + n0 + b_i1);
  };

  ldA(0, pa); ldB(0, pb);
  for (int kc = 0; kc < nchunk; ++kc) {
    *(s8v*)&a_s[a_i0][a_i1] = pa;
    {
      const bf16* e = (const bf16*)&pb;
      #pragma unroll
      for (int j = 0; j < 8; ++j) b_s[b_i1 + j][b_i0] = e[j];
    }
    __syncthreads();
    if (kc + 1 < nchunk) { ldA(kc + 1, pa); ldB(kc + 1, pb); }
    s8v af = *(const s8v*)&a_s[w * 16 + l15][oct * 8];
    #pragma unroll
    for (int nt = 0; nt < 4; ++nt) {
      s8v bfr = *(const s8v*)&b_s[nt * 16 + l15][oct * 8];
      acc[nt] = __builtin_amdgcn_mfma_f32_16x16x32_bf16(af, bfr, acc[nt], 0, 0, 0);
    }
    __syncthreads();
  }
  const int gm_base = m0 + w * 16 + oct * 4;
  #pragma unroll
  for (int nt = 0; nt < 4; ++nt) {
    const int gn = n0 + nt * 16 + l15;
    #pragma unroll
    for (int r = 0; r < 4; ++r) {
      int gm = gm_base + r;
      if (gm < M) {
        float vv = acc[nt][r] + biasu[gm];
        if (QKT && gm < 64) {
          float vv2 = (gm < 32) ? vv * 1.44269504f : vv;   // q *= log2(e)
          qkt[(long)gn * 64 + gm] = __float2bfloat16(vv2);
        } else {
          Cm[(long)gm * N + gn] = __float2bfloat16(vv);
        }
      }
    }
  }
}

// ---------------------------------------------------------------------------
// Stage-C projection, merged: grid (64 n, 5, 2 batch).  (R11 body.)
// y==0: qk-proj (wqk fp32, B=u2) -> qkt (transposed, q rows * log2e).
// y>=1: v-proj  (wv fp32, B=u3, m0=(y-1)*64) -> qkv V rows.
// ---------------------------------------------------------------------------
__global__ __launch_bounds__(256) void projc_k(
    const float* __restrict__ wqk, const float* __restrict__ bqk,
    const bf16* __restrict__ u2,
    const float* __restrict__ wv, const float* __restrict__ bvv,
    const bf16* __restrict__ u3,
    bf16* __restrict__ qkv, bf16* __restrict__ qkt)
{
  __shared__ bf16 a_s[64][40];
  __shared__ bf16 b_s[64][40];
  const int tid = threadIdx.x;
  const int bat = blockIdx.z;
  const int qkmode = (blockIdx.y == 0);
  const float* Au    = qkmode ? wqk : wv;
  const float* biasu = qkmode ? bqk : bvv;
  const bf16* Bm     = (qkmode ? u2 : u3) + (long)bat * CNL;
  const int M  = qkmode ? 64 : 256;
  const int m0 = qkmode ? 0 : (blockIdx.y - 1) * 64;
  const int n0 = blockIdx.x * 64;
  const int w = tid >> 6, lane = tid & 63;
  const int l15 = lane & 15, oct = lane >> 4;

  f4v acc[4];
  #pragma unroll
  for (int i = 0; i < 4; ++i) acc[i] = (f4v){0.f, 0.f, 0.f, 0.f};

  const int a_i0 = tid >> 2, a_i1 = (tid & 3) * 8;
  const int b_i0 = tid >> 3, b_i1 = (tid & 7) * 8;

  s8v pa, pb;
  auto ldA = [&](int kc, s8v& d) {
    if (m0 + a_i0 < M) d = ld8(Au + (long)(m0 + a_i0) * 256 + kc * 32 + a_i1);
    else d = (s8v){0,0,0,0,0,0,0,0};
  };
  auto ldB = [&](int kc, s8v& d) {
    d = ld8(Bm + (long)(kc * 32 + b_i0) * NPIX + n0 + b_i1);
  };

  ldA(0, pa); ldB(0, pb);
  for (int kc = 0; kc < 8; ++kc) {
    *(s8v*)&a_s[a_i0][a_i1] = pa;
    {
      const bf16* e = (const bf16*)&pb;
      #pragma unroll
      for (int j = 0; j < 8; ++j) b_s[b_i1 + j][b_i0] = e[j];
    }
    __syncthreads();
    if (kc + 1 < 8) { ldA(kc + 1, pa); ldB(kc + 1, pb); }
    s8v af = *(const s8v*)&a_s[w * 16 + l15][oct * 8];
    #pragma unroll
    for (int nt = 0; nt < 4; ++nt) {
      s8v bfr = *(const s8v*)&b_s[nt * 16 + l15][oct * 8];
      acc[nt] = __builtin_amdgcn_mfma_f32_16x16x32_bf16(af, bfr, acc[nt], 0, 0, 0);
    }
    __syncthreads();
  }
  const int gm_base = m0 + w * 16 + oct * 4;
  #pragma unroll
  for (int nt = 0; nt < 4; ++nt) {
    const int gn = n0 + nt * 16 + l15;
    #pragma unroll
    for (int r = 0; r < 4; ++r) {
      int gm = gm_base + r;
      if (gm < M) {
        float vv = acc[nt][r] + biasu[gm];
        if (qkmode) {
          float vv2 = (gm < 32) ? vv * 1.44269504f : vv;   // q *= log2(e)
          qkt[(long)bat * QKTSTR + (long)gn * 64 + gm] = __float2bfloat16(vv2);
        } else {
          qkv[64 * NPIX + (long)bat * QKVSTR + (long)gm * NPIX + gn] = __float2bfloat16(vv);
        }
      }
    }
  }
}

// ---------------------------------------------------------------------------
// Merged prep: cvtw2 (both convs) + cat x2 (320-row) + cat qk (64-row).
// ---------------------------------------------------------------------------
__global__ __launch_bounds__(256) void prep_k(
    const float* __restrict__ cw1, const float* __restrict__ cw2,
    bf16* __restrict__ o1, bf16* __restrict__ o2,
    const float* __restrict__ q1, const float* __restrict__ qb1,
    const float* __restrict__ k1, const float* __restrict__ kb1,
    const float* __restrict__ v1, const float* __restrict__ vb1,
    float* __restrict__ wcat1, float* __restrict__ bcat1,
    const float* __restrict__ q2, const float* __restrict__ qb2,
    const float* __restrict__ k2, const float* __restrict__ kb2,
    const float* __restrict__ v2, const float* __restrict__ vb2,
    float* __restrict__ wcat2, float* __restrict__ bcat2,
    const float* __restrict__ qq, const float* __restrict__ qqb,
    const float* __restrict__ kk, const float* __restrict__ kkb,
    float* __restrict__ wqk, float* __restrict__ bqk)
{
  long idx = (long)blockIdx.x * 256 + threadIdx.x;
  if (idx < 1179648) {
    const float* in = (idx < 589824) ? cw1 : cw2;
    bf16* out = (idx < 589824) ? o1 : o2;
    long i = (idx < 589824) ? idx : idx - 589824;
    int o = (int)(i / 2304), r = (int)(i % 2304);
    int j = r >> 8, c = r & 255;
    out[i] = __float2bfloat16(in[(o * 256 + c) * 9 + j]);
    return;
  }
  idx -= 1179648;
  const float *wq, *bq, *wk, *bk, *wv, *bv;
  float *wcat, *bcat; int M;
  if (idx < 82240) {
    wq = q1; bq = qb1; wk = k1; bk = kb1; wv = v1; bv = vb1;
    wcat = wcat1; bcat = bcat1; M = 320;
  } else if (idx < 164480) {
    idx -= 82240;
    wq = q2; bq = qb2; wk = k2; bk = kb2; wv = v2; bv = vb2;
    wcat = wcat2; bcat = bcat2; M = 320;
  } else if (idx < 180928) {
    idx -= 164480;
    wq = qq; bq = qqb; wk = kk; bk = kkb; wv = nullptr; bv = nullptr;
    wcat = wqk; bcat = bqk; M = 64;
  } else return;
  int total = M << 8;
  if (idx < total) {
    int r = (int)(idx >> 8), c = (int)(idx & 255);
    float v;
    if (r < 32) v = wq[r * 256 + c];
    else if (r < 64) v = wk[(r - 32) * 256 + c];
    else v = wv[(r - 64) * 256 + c];
    wcat[idx] = v;
  } else if (idx < total + M) {
    int r = (int)(idx - total);
    bcat[r] = (r < 32) ? bq[r] : (r < 64) ? bk[r - 32] : bv[r - 64];
  }
}

// ---- 16-elem row load/store helpers ----------------------------------------
__device__ inline void ld16(const bf16* p, float* v) {
  s8v r0 = *(const s8v*)p, r1 = *(const s8v*)(p + 8);
  const bf16* e0 = (const bf16*)&r0; const bf16* e1 = (const bf16*)&r1;
  #pragma unroll
  for (int j = 0; j < 8; ++j) { v[j] = __bfloat162float(e0[j]); v[8 + j] = __bfloat162float(e1[j]); }
}
__device__ inline void ld16(const float* p, float* v) {
  #pragma unroll
  for (int q = 0; q < 4; ++q) {
    float4 f = *(const float4*)(p + q * 4);
    v[q * 4 + 0] = f.x; v[q * 4 + 1] = f.y; v[q * 4 + 2] = f.z; v[q * 4 + 3] = f.w;
  }
}
__device__ inline void st16(bf16* p, const float* v) {
  s8v o0, o1v; bf16* f0 = (bf16*)&o0; bf16* f1 = (bf16*)&o1v;
  #pragma unroll
  for (int j = 0; j < 8; ++j) { f0[j] = __float2bfloat16(v[j]); f1[j] = __float2bfloat16(v[8 + j]); }
  *(s8v*)p = o0; *(s8v*)(p + 8) = o1v;
}
__device__ inline void st16(float* p, const float* v) {
  #pragma unroll
  for (int q = 0; q < 4; ++q) {
    float4 f; f.x = v[q * 4 + 0]; f.y = v[q * 4 + 1]; f.z = v[q * 4 + 2]; f.w = v[q * 4 + 3];
    *(float4*)(p + q * 4) = f;
  }
}

// ---- fused InstanceNorm: out = inorm(g*a + b) per row of 4096 --------------
template<typename TAe, typename TBe, typename TOe, int G>
__global__ __launch_bounds__(256) void inorm_k(
    const TAe* __restrict__ a, const TBe* __restrict__ b,
    const float* __restrict__ g, TOe* __restrict__ out)
{
  __shared__ float red[8];
  const int tid = threadIdx.x;
  const long base = (long)blockIdx.x * NPIX + tid * 16;
  float gv = G ? *g : 1.f;
  float va[16], vbv[16], v[16];
  ld16(a + base, va);
  ld16(b + base, vbv);
  #pragma unroll
  for (int j = 0; j < 16; ++j) v[j] = gv * va[j] + vbv[j];
  float sum = 0.f, sq = 0.f;
  #pragma unroll
  for (int j = 0; j < 16; ++j) { sum += v[j]; sq += v[j] * v[j]; }
  #pragma unroll
  for (int s = 32; s; s >>= 1) { sum += __shfl_xor(sum, s); sq += __shfl_xor(sq, s); }
  if ((tid & 63) == 0) { red[tid >> 6] = sum; red[4 + (tid >> 6)] = sq; }
  __syncthreads();
  sum = red[0] + red[1] + red[2] + red[3];
  sq  = red[4] + red[5] + red[6] + red[7];
  float mean = sum * (1.f / NPIX);
  float var  = fmaxf(sq * (1.f / NPIX) - mean * mean, 0.f);
  float rstd = rsqrtf(var + 1e-5f);
  float o[16];
  #pragma unroll
  for (int j = 0; j < 16; ++j) o[j] = (v[j] - mean) * rstd;
  st16(out + base, o);
}

// ---- two independent InstanceNorms in one launch (both bf16+float, G=1) ----
__global__ __launch_bounds__(256) void inorm2_k(
    const bf16* __restrict__ a0, const float* __restrict__ b0,
    const float* __restrict__ g0, bf16* __restrict__ o0,
    const bf16* __restrict__ a1, const float* __restrict__ b1,
    const float* __restrict__ g1, bf16* __restrict__ o1)
{
  __shared__ float red[8];
  const int tid = threadIdx.x;
  const int sel = blockIdx.x >> 9;
  const int row = blockIdx.x & 511;
  const bf16* a = sel ? a1 : a0;
  const float* b = sel ? b1 : b0;
  const float* g = sel ? g1 : g0;
  bf16* out = sel ? o1 : o0;
  const long base = (long)row * NPIX + tid * 16;
  float gv = *g;
  float va[16], vbv[16], v[16];
  ld16(a + base, va);
  ld16(b + base, vbv);
  #pragma unroll
  for (int j = 0; j < 16; ++j) v[j] = gv * va[j] + vbv[j];
  float sum = 0.f, sq = 0.f;
  #pragma unroll
  for (int j = 0; j < 16; ++j) { sum += v[j]; sq += v[j] * v[j]; }
  #pragma unroll
  for (int s = 32; s; s >>= 1) { sum += __shfl_xor(sum, s); sq += __shfl_xor(sq, s); }
  if ((tid & 63) == 0) { red[tid >> 6] = sum; red[4 + (tid >> 6)] = sq; }
  __syncthreads();
  sum = red[0] + red[1] + red[2] + red[3];
  sq  = red[4] + red[5] + red[6] + red[7];
  float mean = sum * (1.f / NPIX);
  float var  = fmaxf(sq * (1.f / NPIX) - mean * mean, 0.f);
  float rstd = rsqrtf(var + 1e-5f);
  float o[16];
  #pragma unroll
  for (int j = 0; j < 16; ++j) o[j] = (v[j] - mean) * rstd;
  st16(out + base, o);
}

// ---- fused dependent pair: u4 = inorm(inorm(g*t0 + y) + u3) ----------------
__global__ __launch_bounds__(256) void inorm_pair_k(
    const bf16* __restrict__ t0, const float* __restrict__ y,
    const float* __restrict__ g, const bf16* __restrict__ u3,
    bf16* __restrict__ u4)
{
  __shared__ float red[16];
  const int tid = threadIdx.x;
  const long base = (long)blockIdx.x * NPIX + tid * 16;
  float gv = *g;
  float va[16], vbv[16], v[16];
  ld16(t0 + base, va);
  ld16(y + base, vbv);
  #pragma unroll
  for (int j = 0; j < 16; ++j) v[j] = gv * va[j] + vbv[j];
  float sum = 0.f, sq = 0.f;
  #pragma unroll
  for (int j = 0; j < 16; ++j) { sum += v[j]; sq += v[j] * v[j]; }
  #pragma unroll
  for (int s = 32; s; s >>= 1) { sum += __shfl_xor(sum, s); sq += __shfl_xor(sq, s); }
  if ((tid & 63) == 0) { red[tid >> 6] = sum; red[4 + (tid >> 6)] = sq; }
  __syncthreads();
  sum = red[0] + red[1] + red[2] + red[3];
  sq  = red[4] + red[5] + red[6] + red[7];
  float mean = sum * (1.f / NPIX);
  float var  = fmaxf(sq * (1.f / NPIX) - mean * mean, 0.f);
  float rstd = rsqrtf(var + 1e-5f);
  // second stage: w = o1 + u3, stats again
  float vu[16];
  ld16(u3 + base, vu);
  #pragma unroll
  for (int j = 0; j < 16; ++j) v[j] = (v[j] - mean) * rstd + vu[j];
  sum = 0.f; sq = 0.f;
  #pragma unroll
  for (int j = 0; j < 16; ++j) { sum += v[j]; sq += v[j] * v[j]; }
  #pragma unroll
  for (int s = 32; s; s >>= 1) { sum += __shfl_xor(sum, s); sq += __shfl_xor(sq, s); }
  if ((tid & 63) == 0) { red[8 + (tid >> 6)] = sum; red[12 + (tid >> 6)] = sq; }
  __syncthreads();
  sum = red[8] + red[9] + red[10] + red[11];
  sq  = red[12] + red[13] + red[14] + red[15];
  mean = sum * (1.f / NPIX);
  var  = fmaxf(sq * (1.f / NPIX) - mean * mean, 0.f);
  rstd = rsqrtf(var + 1e-5f);
  float o[16];
  #pragma unroll
  for (int j = 0; j < 16; ++j) o[j] = (v[j] - mean) * rstd;
  st16(u4 + base, o);
}

// ---- host-side helpers ------------------------------------------------------
static const long CN = CNL;

// fused flash attention: CB picked so both launches are 512 blocks (2/CU).
static void attn_core(int nb, bf16* qkv, bf16* qkt, bf16* t0, hipStream_t stream)
{
  if (nb == 4)
    fattn_k<128><<<dim3(64, 2, 4), dim3(512), 0, stream>>>(qkt, qkv + 64 * NPIX, t0);
  else
    fattn_k<64><<<dim3(64, 4, 2), dim3(512), 0, stream>>>(qkt, qkv + 64 * NPIX, t0);
}

static void run_conv(const bf16* src, const bf16* wcvt, const float* cb,
                     bf16* dst, hipStream_t stream)
{
  conv_k<<<dim3(64, 4, 2), dim3(256), 0, stream>>>(src, wcvt, cb, dst);
}

// ---------------------------------------------------------------------------
extern "C" void kernel_launch(void* const* d_in, const int* in_sizes, int n_in,
                              void* d_out, int out_size, void* d_ws, size_t ws_size,
                              hipStream_t stream)
{
  (void)in_sizes; (void)n_in; (void)out_size; (void)ws_size;
  const float* x = (const float*)d_in[0];
  const float* y = (const float*)d_in[1];
  auto W = [&](int i) { return (const float*)d_in[i]; };

  char* wp = (char*)d_ws;
  auto take = [&](size_t nbytes) { char* p = wp; wp += (nbytes + 255) & ~(size_t)255; return p; };
  bf16*  qkv   = (bf16*)take((size_t)4 * QKVSTR * 2);
  bf16*  qkt   = (bf16*)take((size_t)4 * QKTSTR * 2);
  bf16*  t0    = (bf16*)take((size_t)4 * CN * 2);
  bf16*  u1    = (bf16*)take(2 * CN * 2);
  bf16*  u2    = (bf16*)take(2 * CN * 2);
  bf16*  u3    = (bf16*)take(2 * CN * 2);
  bf16*  u4    = (bf16*)take(2 * CN * 2);
  bf16*  wcvt1 = (bf16*)take((size_t)589824 * 2);
  bf16*  wcvt2 = (bf16*)take((size_t)589824 * 2);
  float* wcat1 = (float*)take((size_t)81920 * 4);
  float* bcat1 = (float*)take(320 * 4);
  float* wcat2 = (float*)take((size_t)81920 * 4);
  float* bcat2 = (float*)take(320 * 4);
  float* wqk   = (float*)take((size_t)16384 * 4);
  float* bqk   = (float*)take(64 * 4);
  bf16*  cvout = qkv;                                         // conv out (aliased)

  dim3 TB(256);

  // ---- prep: all weight concat/convert in one launch ----
  prep_k<<<dim3(5315), TB, 0, stream>>>(
      W(23), W(25), wcvt1, wcvt2,
      W(2), W(3), W(4), W(5), W(6), W(7), wcat1, bcat1,
      W(9), W(10), W(11), W(12), W(13), W(14), wcat2, bcat2,
      W(16), W(17), W(18), W(19), wqk, bqk);

  // ---- stages A+B attention together: z = stage*2 + batch ----
  proj_k<1,float><<<dim3(64,5,4), TB, 0, stream>>>(
      wcat1, wcat2, x, y, bcat1, bcat2, qkv, qkt, 320, NPIX, 256, CN, QKVSTR, 8);
  attn_core(4, qkv, qkt, t0, stream);

  // ---- out_1 / out_3 inorms (merged) ----
  inorm2_k<<<dim3(1024), TB, 0, stream>>>(t0, x, W(8), u1,
                                          t0 + 2 * CN, y, W(15), u3);

  // ---- conv1 -> out_2 ----
  run_conv(u1, wcvt1, W(24), cvout, stream);
  inorm_k<bf16,bf16,bf16,0><<<dim3(512), TB, 0, stream>>>(u1, cvout, nullptr, u2);

  // ---- stage C: merged projection (qk from out_2, v from out_3) ----
  projc_k<<<dim3(64, 5, 2), TB, 0, stream>>>(
      wqk, bqk, u2, W(20), W(21), u3, qkv, qkt);
  attn_core(2, qkv, qkt, t0, stream);
  // fused: u4 = inorm(inorm(g*t0 + y) + u3)
  inorm_pair_k<<<dim3(512), TB, 0, stream>>>(t0, y, W(22), u3, u4);
  run_conv(u4, wcvt2, W(26), cvout, stream);
  inorm_k<bf16,bf16,float,0><<<dim3(512), TB, 0, stream>>>(u4, cvout, nullptr, (float*)d_out);
}

// Round 14
// 332.299 us; speedup vs baseline: 1.2481x; 1.0453x over previous
//
#include <hip/hip_runtime.h>
#include <hip/hip_bf16.h>

typedef __hip_bfloat16 bf16;
typedef __attribute__((ext_vector_type(8))) short s8v;   // 8 bf16 = 4 VGPRs
typedef __attribute__((ext_vector_type(4))) short s4v;   // 4 bf16 = 8 bytes
typedef __attribute__((ext_vector_type(4))) float f4v;

#define NPIX 4096
#define CDIM 256
#define MN_ELEMS (1 << 20)        // CDIM * NPIX
#define QKVSTR (320L * NPIX)      // qkv per-slot stride (elems)
#define QKTSTR (64L * NPIX)       // qkt per-slot stride (elems)
#define CNL ((long)CDIM * NPIX)

#if __has_builtin(__builtin_amdgcn_exp2f)
#define EXP2F(x) __builtin_amdgcn_exp2f(x)
#else
#define EXP2F(x) exp2f(x)
#endif

// ---- async global->LDS, 16B per lane (dest = wave-uniform base + lane*16) ---
typedef __attribute__((address_space(1))) const unsigned int g_u32;
typedef __attribute__((address_space(3))) unsigned int l_u32;
__device__ __forceinline__ void glds16(const void* g, void* l) {
  __builtin_amdgcn_global_load_lds((g_u32*)g, (l_u32*)l, 16, 0, 0);
}

// ---- 8-element loaders -> bf16x8 (s8v) --------------------------------------
__device__ inline s8v ld8(const bf16* p) { return *(const s8v*)p; }
__device__ inline s8v ld8(const float* p) {
  float4 f0 = *(const float4*)p;
  float4 f1 = *(const float4*)(p + 4);
  s8v r; bf16* e = (bf16*)&r;
  e[0] = __float2bfloat16(f0.x); e[1] = __float2bfloat16(f0.y);
  e[2] = __float2bfloat16(f0.z); e[3] = __float2bfloat16(f0.w);
  e[4] = __float2bfloat16(f1.x); e[5] = __float2bfloat16(f1.y);
  e[6] = __float2bfloat16(f1.z); e[7] = __float2bfloat16(f1.w);
  return r;
}

// ---------------------------------------------------------------------------
// Fused flash-style attention — 8 thin waves (512 thr), all LDS streams
// XOR-swizzled, counted-vmcnt pipeline (2 raw barriers/iter, K dbuf).
// (R10/R11 kernel, verified: 65.6 us merged, 2.1M bank conflicts.)
// ---------------------------------------------------------------------------
template<int CB>
__global__ __launch_bounds__(512) void fattn_k(
    const bf16* __restrict__ qkt, const bf16* __restrict__ Vg,
    bf16* __restrict__ out)
{
  constexpr int SC = CB / 64;          // PV c-frags per wave
  __shared__ bf16 k_s[2][128 * 32];    // [buf][m 128][32] (swizzled rows)
  __shared__ bf16 v_s[4 * CB * 32];    // [kk][c CB][32] (swizzled rows)
  __shared__ bf16 p_s[4 * 64 * 32];    // [kk][n 64][32 m] (swizzled rows)
  __shared__ float sums[4 * 64];       // [m-quarter][n]

  const int tid = threadIdx.x;
  const int z = blockIdx.z;
  const int w = tid >> 6, lane = tid & 63;
  const int l15 = lane & 15, oct = lane >> 4;
  const int wr2 = w >> 2, wc2 = w & 3;     // S roles
  const int pc = w >> 1, pn = w & 1;       // PV roles
  const int n0 = blockIdx.x * 64, c0 = blockIdx.y * CB;
  const bf16* qk = qkt + (long)z * QKTSTR;
  const bf16* Vz = Vg + (long)z * QKVSTR;

  // staging source column pre-swizzle: row = tid>>2, quarter = tid&3
  const int t2 = tid >> 2;
  const int kq3 = ((tid & 3) ^ ((t2 >> 1) & 3)) * 8;      // for k_s / Q (row=t2)
  const int vrow = t2 & (CB - 1);                          // v_s row
  const int vq3 = ((tid & 3) ^ ((vrow >> 1) & 3)) * 8;     // for v_s

  auto stageK = [&](int m, int buf) {
    glds16(qk + (long)(m + t2) * 64 + 32 + kq3, &k_s[buf][tid * 8]);
  };
  auto stageV = [&](int m) {
    #pragma unroll
    for (int it = 0; it < CB / 32; ++it) {
      const int flat = it * 4096 + tid * 8;
      const int g = flat / (CB * 32);
      glds16(Vz + (long)(c0 + vrow) * 4096 + m + g * 32 + vq3, v_s + flat);
    }
  };

  // ---- prologue: stage Q (tid<256 -> p_s rows 0..63, swizzled), K(0), V(0) --
  if (tid < 256)
    glds16(qk + (long)(n0 + t2) * 64 + kq3, p_s + tid * 8);
  stageK(0, 0);
  stageV(0);
  __syncthreads();   // full drain once (prologue)

  s8v qf[2];
  #pragma unroll
  for (int st = 0; st < 2; ++st) {
    const int row = wr2 * 32 + st * 16 + l15;
    int byte = row * 64 + oct * 16;
    byte ^= ((row >> 1) & 3) << 4;
    qf[st] = *(const s8v*)((const char*)p_s + byte);
  }
  __syncthreads();   // all qf reads done before p_s is overwritten by P(0)

  f4v acc[SC][2];
  #pragma unroll
  for (int i = 0; i < SC; ++i)
    #pragma unroll
    for (int j = 0; j < 2; ++j) acc[i][j] = (f4v){0.f, 0.f, 0.f, 0.f};
  float rs[2] = {0.f, 0.f};

  for (int i = 0; i < 32; ++i) {
    const int cur = i & 1;
    if (i < 31) stageK((i + 1) * 128, cur ^ 1);   // in flight across this iter

    // ---- S^T phase: S[m][n] = k.q (q pre-scaled by log2e), exp2, pack -----
    s8v kf[2];
    #pragma unroll
    for (int nt = 0; nt < 2; ++nt) {
      const int row = wc2 * 32 + nt * 16 + l15;
      int byte = row * 64 + oct * 16;
      byte ^= ((row >> 1) & 3) << 4;
      kf[nt] = *(const s8v*)((const char*)&k_s[cur][0] + byte);
    }
    #pragma unroll
    for (int st = 0; st < 2; ++st) {
      const int n = wr2 * 32 + st * 16 + l15;          // P row (lane-fixed)
      const int sw = ((n >> 1) & 3) << 4;              // intra-row byte XOR
      f4v sa[2];
      __builtin_amdgcn_s_setprio(1);
      #pragma unroll
      for (int nt = 0; nt < 2; ++nt) {
        f4v zz = (f4v){0.f, 0.f, 0.f, 0.f};
        sa[nt] = __builtin_amdgcn_mfma_f32_16x16x32_bf16(kf[nt], qf[st], zz, 0, 0, 0);
      }
      __builtin_amdgcn_s_setprio(0);
      #pragma unroll
      for (int nt = 0; nt < 2; ++nt) {
        // m = wc2*32 + nt*16 + oct*4 + r  ->  kk = wc2
        int byte = wc2 * 4096 + n * 64 + nt * 32 + oct * 8;
        byte ^= sw;
        s4v pk; bf16* pe = (bf16*)&pk;
        float rsum = 0.f;
        #pragma unroll
        for (int r = 0; r < 4; ++r) {
          float e = EXP2F(sa[nt][r]);
          rsum += e;
          pe[r] = __float2bfloat16(e);
        }
        rs[st] += rsum;
        *(s4v*)((char*)p_s + byte) = pk;
      }
    }
    // ---- W1: V(i) landed + P visible; K(i+1) stays in flight --------------
    if (i < 31) asm volatile("s_waitcnt vmcnt(1) lgkmcnt(0)" ::: "memory");
    else        asm volatile("s_waitcnt vmcnt(0) lgkmcnt(0)" ::: "memory");
    __builtin_amdgcn_sched_barrier(0);
    __builtin_amdgcn_s_barrier();

    // ---- PV phase: acc[c][n] += V[c][m] * P[n][m], K=128 ------------------
    #pragma unroll
    for (int kk = 0; kk < 4; ++kk) {
      s8v vf[SC], pf[2];
      #pragma unroll
      for (int st = 0; st < SC; ++st) {
        const int row = pc * (CB / 4) + st * 16 + l15;
        int byte = kk * (CB * 64) + row * 64 + oct * 16;
        byte ^= ((row >> 1) & 3) << 4;
        vf[st] = *(const s8v*)((const char*)v_s + byte);
      }
      #pragma unroll
      for (int nt = 0; nt < 2; ++nt) {
        const int n = pn * 32 + nt * 16 + l15;
        int byte = kk * 4096 + n * 64 + oct * 16;
        byte ^= ((n >> 1) & 3) << 4;
        pf[nt] = *(const s8v*)((const char*)p_s + byte);
      }
      __builtin_amdgcn_s_setprio(1);
      #pragma unroll
      for (int st = 0; st < SC; ++st)
        #pragma unroll
        for (int nt = 0; nt < 2; ++nt)
          acc[st][nt] = __builtin_amdgcn_mfma_f32_16x16x32_bf16(vf[st], pf[nt], acc[st][nt], 0, 0, 0);
      __builtin_amdgcn_s_setprio(0);
    }
    // ---- W2: K(i+1) landed (cover = S+PV); then restage V -----------------
    asm volatile("s_waitcnt vmcnt(0)" ::: "memory");
    __builtin_amdgcn_sched_barrier(0);
    __builtin_amdgcn_s_barrier();

    if (i < 31) stageV((i + 1) * 128);   // drains at next iter's W1
  }

  // ---- row-sum: reduce over octs, combine 4 m-quarters via LDS ------------
  #pragma unroll
  for (int st = 0; st < 2; ++st) {
    rs[st] += __shfl_xor(rs[st], 16);
    rs[st] += __shfl_xor(rs[st], 32);
  }
  if (lane < 16) {
    #pragma unroll
    for (int st = 0; st < 2; ++st)
      sums[wc2 * 64 + wr2 * 32 + st * 16 + l15] = rs[st];
  }
  __syncthreads();

  float rinv[2];
  #pragma unroll
  for (int nt = 0; nt < 2; ++nt) {
    const int n = pn * 32 + nt * 16 + l15;
    rinv[nt] = 1.f / (sums[n] + sums[64 + n] + sums[128 + n] + sums[192 + n]);
  }
  bf16* op = out + (long)z * CNL;
  #pragma unroll
  for (int st = 0; st < SC; ++st) {
    const int gc = c0 + pc * (CB / 4) + st * 16 + oct * 4;
    #pragma unroll
    for (int nt = 0; nt < 2; ++nt) {
      const int gn = n0 + pn * 32 + nt * 16 + l15;
      #pragma unroll
      for (int r = 0; r < 4; ++r)
        op[(long)(gc + r) * NPIX + gn] = __float2bfloat16(acc[st][nt][r] * rinv[nt]);
    }
  }
}

// ---------------------------------------------------------------------------
// Fused direct 3x3 conv (R7/R11 body, the config inside the 337.7 best):
// 512 threads, grid (64 h, 2 o-half, 2 batch).
// LDS tile [row 3][wpos 66][c 64] (wpos stride 66 = conflict-free), 26.1 KB.
// ---------------------------------------------------------------------------
__global__ __launch_bounds__(512) void conv_k(
    const bf16* __restrict__ x, const bf16* __restrict__ wcvt,
    const float* __restrict__ bias, bf16* __restrict__ out)
{
  __shared__ bf16 lds[3 * 66 * 66];   // [row][wpos][c(64, 2 pad)]
  const int tid = threadIdx.x;
  const int h = blockIdx.x;
  const int o0 = blockIdx.y * 128;
  x   += (long)blockIdx.z * CDIM * NPIX;
  out += (long)blockIdx.z * CDIM * NPIX;

  const int w = tid >> 6, lane = tid & 63;
  const int l15 = lane & 15, oct = lane >> 4;

  // zero the w-pad columns once (wpos 0 and 65; never overwritten by staging)
  if (tid < 192) {
    int row = tid >> 6, c = tid & 63;
    lds[(row * 66 + 0) * 66 + c] = __float2bfloat16(0.f);
    lds[(row * 66 + 65) * 66 + c] = __float2bfloat16(0.f);
  }

  f4v acc[4];
  #pragma unroll
  for (int nf = 0; nf < 4; ++nf) acc[nf] = (f4v){0.f, 0.f, 0.f, 0.f};

  const int w2 = tid & 31, chi = tid >> 5;   // staging: w2 pixel-pair, chi c-sub
  const long arow = (long)(o0 + w * 16 + l15) * 2304;

  for (int cg = 0; cg < 4; ++cg) {
    __syncthreads();   // pad/compute(cg-1) reads done before overwrite
    #pragma unroll
    for (int it = 0; it < 12; ++it) {
      int row = it >> 2, cgi = it & 3;
      int c = cgi * 16 + chi;
      int hh = h + row - 1;
      unsigned int pix = 0;
      if ((unsigned)hh < 64u)
        pix = *(const unsigned int*)(x + (long)(cg * 64 + c) * 4096 + hh * 64 + w2 * 2);
      const bf16* pp = (const bf16*)&pix;
      lds[(row * 66 + (w2 * 2 + 1)) * 66 + c] = pp[0];
      lds[(row * 66 + (w2 * 2 + 2)) * 66 + c] = pp[1];
    }
    __syncthreads();   // tile(cg) ready

    #pragma unroll
    for (int j = 0; j < 9; ++j) {
      const int dy = j / 3, dx = j % 3;
      #pragma unroll
      for (int kc = 0; kc < 2; ++kc) {
        s8v af = *(const s8v*)(wcvt + arow + j * 256 + cg * 64 + kc * 32 + oct * 8);
        s8v bfv[4];
        #pragma unroll
        for (int nf = 0; nf < 4; ++nf)
          bfv[nf] = *(const s8v*)&lds[(dy * 66 + (nf * 16 + l15 + dx)) * 66 + kc * 32 + oct * 8];
        #pragma unroll
        for (int nf = 0; nf < 4; ++nf)
          acc[nf] = __builtin_amdgcn_mfma_f32_16x16x32_bf16(af, bfv[nf], acc[nf], 0, 0, 0);
      }
    }
  }

  // ---- epilogue: + bias, store ----
  #pragma unroll
  for (int nf = 0; nf < 4; ++nf) {
    const int gn = h * 64 + nf * 16 + l15;
    const int go = o0 + w * 16 + oct * 4;
    #pragma unroll
    for (int r = 0; r < 4; ++r)
      out[(long)(go + r) * NPIX + gn] = __float2bfloat16(acc[nf][r] + bias[go + r]);
  }
}

// ---------------------------------------------------------------------------
// Projection GEMM (A+B stages). z = slot; stage = z>>1 selects param set;
// batch = z&1 offsets B. QKT=1: rows gm<64 -> qkt transposed, q rows scaled
// by log2(e).  (R11 body, unswizzled b_s.)
// ---------------------------------------------------------------------------
template<int QKT, typename TBe>
__global__ __launch_bounds__(256) void proj_k(
    const float* __restrict__ A, const float* __restrict__ A2,
    const TBe* __restrict__ B1, const TBe* __restrict__ B2,
    const float* __restrict__ bias, const float* __restrict__ bias2,
    bf16* __restrict__ Cm, bf16* __restrict__ qkt,
    int M, int N, int K, long bbat, long cbat, int nchunk)
{
  __shared__ bf16 a_s[64][40];
  __shared__ bf16 b_s[64][40];
  const int tid = threadIdx.x;
  const int z = blockIdx.z, stage = z >> 1, bat = z & 1;
  const float* Au = stage ? A2 : A;
  const float* biasu = stage ? bias2 : bias;
  const TBe* Bm = (stage ? B2 : B1) + bat * bbat;
  Cm += z * cbat;
  if (QKT) qkt += z * QKTSTR;
  const int m0 = blockIdx.y * 64, n0 = blockIdx.x * 64;
  const int w = tid >> 6, lane = tid & 63;
  const int l15 = lane & 15, oct = lane >> 4;

  f4v acc[4];
  #pragma unroll
  for (int i = 0; i < 4; ++i) acc[i] = (f4v){0.f, 0.f, 0.f, 0.f};

  const int a_i0 = tid >> 2, a_i1 = (tid & 3) * 8;
  const int b_i0 = tid >> 3, b_i1 = (tid & 7) * 8;

  s8v pa, pb;
  auto ldA = [&](int kc, s8v& d) {
    if (m0 + a_i0 < M) d = ld8(Au + (long)(m0 + a_i0) * K + kc * 32 + a_i1);
    else d = (s8v){0,0,0,0,0,0,0,0};
  };
  auto ldB = [&](int kc, s8v& d) {
    d = ld8(Bm + (long)(kc * 32 + b_i0) * N + n0 + b_i1);
  };

  ldA(0, pa); ldB(0, pb);
  for (int kc = 0; kc < nchunk; ++kc) {
    *(s8v*)&a_s[a_i0][a_i1] = pa;
    {
      const bf16* e = (const bf16*)&pb;
      #pragma unroll
      for (int j = 0; j < 8; ++j) b_s[b_i1 + j][b_i0] = e[j];
    }
    __syncthreads();
    if (kc + 1 < nchunk) { ldA(kc + 1, pa); ldB(kc + 1, pb); }
    s8v af = *(const s8v*)&a_s[w * 16 + l15][oct * 8];
    #pragma unroll
    for (int nt = 0; nt < 4; ++nt) {
      s8v bfr = *(const s8v*)&b_s[nt * 16 + l15][oct * 8];
      acc[nt] = __builtin_amdgcn_mfma_f32_16x16x32_bf16(af, bfr, acc[nt], 0, 0, 0);
    }
    __syncthreads();
  }
  const int gm_base = m0 + w * 16 + oct * 4;
  #pragma unroll
  for (int nt = 0; nt < 4; ++nt) {
    const int gn = n0 + nt * 16 + l15;
    #pragma unroll
    for (int r = 0; r < 4; ++r) {
      int gm = gm_base + r;
      if (gm < M) {
        float vv = acc[nt][r] + biasu[gm];
        if (QKT && gm < 64) {
          float vv2 = (gm < 32) ? vv * 1.44269504f : vv;   // q *= log2(e)
          qkt[(long)gn * 64 + gm] = __float2bfloat16(vv2);
        } else {
          Cm[(long)gm * N + gn] = __float2bfloat16(vv);
        }
      }
    }
  }
}

// ---------------------------------------------------------------------------
// Stage-C projection, merged: grid (64 n, 5, 2 batch).  (R11 body.)
// y==0: qk-proj (wqk fp32, B=u2) -> qkt (transposed, q rows * log2e).
// y>=1: v-proj  (wv fp32, B=u3, m0=(y-1)*64) -> qkv V rows.
// ---------------------------------------------------------------------------
__global__ __launch_bounds__(256) void projc_k(
    const float* __restrict__ wqk, const float* __restrict__ bqk,
    const bf16* __restrict__ u2,
    const float* __restrict__ wv, const float* __restrict__ bvv,
    const bf16* __restrict__ u3,
    bf16* __restrict__ qkv, bf16* __restrict__ qkt)
{
  __shared__ bf16 a_s[64][40];
  __shared__ bf16 b_s[64][40];
  const int tid = threadIdx.x;
  const int bat = blockIdx.z;
  const int qkmode = (blockIdx.y == 0);
  const float* Au    = qkmode ? wqk : wv;
  const float* biasu = qkmode ? bqk : bvv;
  const bf16* Bm     = (qkmode ? u2 : u3) + (long)bat * CNL;
  const int M  = qkmode ? 64 : 256;
  const int m0 = qkmode ? 0 : (blockIdx.y - 1) * 64;
  const int n0 = blockIdx.x * 64;
  const int w = tid >> 6, lane = tid & 63;
  const int l15 = lane & 15, oct = lane >> 4;

  f4v acc[4];
  #pragma unroll
  for (int i = 0; i < 4; ++i) acc[i] = (f4v){0.f, 0.f, 0.f, 0.f};

  const int a_i0 = tid >> 2, a_i1 = (tid & 3) * 8;
  const int b_i0 = tid >> 3, b_i1 = (tid & 7) * 8;

  s8v pa, pb;
  auto ldA = [&](int kc, s8v& d) {
    if (m0 + a_i0 < M) d = ld8(Au + (long)(m0 + a_i0) * 256 + kc * 32 + a_i1);
    else d = (s8v){0,0,0,0,0,0,0,0};
  };
  auto ldB = [&](int kc, s8v& d) {
    d = ld8(Bm + (long)(kc * 32 + b_i0) * NPIX + n0 + b_i1);
  };

  ldA(0, pa); ldB(0, pb);
  for (int kc = 0; kc < 8; ++kc) {
    *(s8v*)&a_s[a_i0][a_i1] = pa;
    {
      const bf16* e = (const bf16*)&pb;
      #pragma unroll
      for (int j = 0; j < 8; ++j) b_s[b_i1 + j][b_i0] = e[j];
    }
    __syncthreads();
    if (kc + 1 < 8) { ldA(kc + 1, pa); ldB(kc + 1, pb); }
    s8v af = *(const s8v*)&a_s[w * 16 + l15][oct * 8];
    #pragma unroll
    for (int nt = 0; nt < 4; ++nt) {
      s8v bfr = *(const s8v*)&b_s[nt * 16 + l15][oct * 8];
      acc[nt] = __builtin_amdgcn_mfma_f32_16x16x32_bf16(af, bfr, acc[nt], 0, 0, 0);
    }
    __syncthreads();
  }
  const int gm_base = m0 + w * 16 + oct * 4;
  #pragma unroll
  for (int nt = 0; nt < 4; ++nt) {
    const int gn = n0 + nt * 16 + l15;
    #pragma unroll
    for (int r = 0; r < 4; ++r) {
      int gm = gm_base + r;
      if (gm < M) {
        float vv = acc[nt][r] + biasu[gm];
        if (qkmode) {
          float vv2 = (gm < 32) ? vv * 1.44269504f : vv;   // q *= log2(e)
          qkt[(long)bat * QKTSTR + (long)gn * 64 + gm] = __float2bfloat16(vv2);
        } else {
          qkv[64 * NPIX + (long)bat * QKVSTR + (long)gm * NPIX + gn] = __float2bfloat16(vv);
        }
      }
    }
  }
}

// ---------------------------------------------------------------------------
// Merged prep: cvtw2 (both convs) + cat x2 (320-row) + cat qk (64-row).
// ---------------------------------------------------------------------------
__global__ __launch_bounds__(256) void prep_k(
    const float* __restrict__ cw1, const float* __restrict__ cw2,
    bf16* __restrict__ o1, bf16* __restrict__ o2,
    const float* __restrict__ q1, const float* __restrict__ qb1,
    const float* __restrict__ k1, const float* __restrict__ kb1,
    const float* __restrict__ v1, const float* __restrict__ vb1,
    float* __restrict__ wcat1, float* __restrict__ bcat1,
    const float* __restrict__ q2, const float* __restrict__ qb2,
    const float* __restrict__ k2, const float* __restrict__ kb2,
    const float* __restrict__ v2, const float* __restrict__ vb2,
    float* __restrict__ wcat2, float* __restrict__ bcat2,
    const float* __restrict__ qq, const float* __restrict__ qqb,
    const float* __restrict__ kk, const float* __restrict__ kkb,
    float* __restrict__ wqk, float* __restrict__ bqk)
{
  long idx = (long)blockIdx.x * 256 + threadIdx.x;
  if (idx < 1179648) {
    const float* in = (idx < 589824) ? cw1 : cw2;
    bf16* out = (idx < 589824) ? o1 : o2;
    long i = (idx < 589824) ? idx : idx - 589824;
    int o = (int)(i / 2304), r = (int)(i % 2304);
    int j = r >> 8, c = r & 255;
    out[i] = __float2bfloat16(in[(o * 256 + c) * 9 + j]);
    return;
  }
  idx -= 1179648;
  const float *wq, *bq, *wk, *bk, *wv, *bv;
  float *wcat, *bcat; int M;
  if (idx < 82240) {
    wq = q1; bq = qb1; wk = k1; bk = kb1; wv = v1; bv = vb1;
    wcat = wcat1; bcat = bcat1; M = 320;
  } else if (idx < 164480) {
    idx -= 82240;
    wq = q2; bq = qb2; wk = k2; bk = kb2; wv = v2; bv = vb2;
    wcat = wcat2; bcat = bcat2; M = 320;
  } else if (idx < 180928) {
    idx -= 164480;
    wq = qq; bq = qqb; wk = kk; bk = kkb; wv = nullptr; bv = nullptr;
    wcat = wqk; bcat = bqk; M = 64;
  } else return;
  int total = M << 8;
  if (idx < total) {
    int r = (int)(idx >> 8), c = (int)(idx & 255);
    float v;
    if (r < 32) v = wq[r * 256 + c];
    else if (r < 64) v = wk[(r - 32) * 256 + c];
    else v = wv[(r - 64) * 256 + c];
    wcat[idx] = v;
  } else if (idx < total + M) {
    int r = (int)(idx - total);
    bcat[r] = (r < 32) ? bq[r] : (r < 64) ? bk[r - 32] : bv[r - 64];
  }
}

// ---- 16-elem row load/store helpers ----------------------------------------
__device__ inline void ld16(const bf16* p, float* v) {
  s8v r0 = *(const s8v*)p, r1 = *(const s8v*)(p + 8);
  const bf16* e0 = (const bf16*)&r0; const bf16* e1 = (const bf16*)&r1;
  #pragma unroll
  for (int j = 0; j < 8; ++j) { v[j] = __bfloat162float(e0[j]); v[8 + j] = __bfloat162float(e1[j]); }
}
__device__ inline void ld16(const float* p, float* v) {
  #pragma unroll
  for (int q = 0; q < 4; ++q) {
    float4 f = *(const float4*)(p + q * 4);
    v[q * 4 + 0] = f.x; v[q * 4 + 1] = f.y; v[q * 4 + 2] = f.z; v[q * 4 + 3] = f.w;
  }
}
__device__ inline void st16(bf16* p, const float* v) {
  s8v o0, o1v; bf16* f0 = (bf16*)&o0; bf16* f1 = (bf16*)&o1v;
  #pragma unroll
  for (int j = 0; j < 8; ++j) { f0[j] = __float2bfloat16(v[j]); f1[j] = __float2bfloat16(v[8 + j]); }
  *(s8v*)p = o0; *(s8v*)(p + 8) = o1v;
}
__device__ inline void st16(float* p, const float* v) {
  #pragma unroll
  for (int q = 0; q < 4; ++q) {
    float4 f; f.x = v[q * 4 + 0]; f.y = v[q * 4 + 1]; f.z = v[q * 4 + 2]; f.w = v[q * 4 + 3];
    *(float4*)(p + q * 4) = f;
  }
}

// ---- fused InstanceNorm: out = inorm(g*a + b) per row of 4096 --------------
template<typename TAe, typename TBe, typename TOe, int G>
__global__ __launch_bounds__(256) void inorm_k(
    const TAe* __restrict__ a, const TBe* __restrict__ b,
    const float* __restrict__ g, TOe* __restrict__ out)
{
  __shared__ float red[8];
  const int tid = threadIdx.x;
  const long base = (long)blockIdx.x * NPIX + tid * 16;
  float gv = G ? *g : 1.f;
  float va[16], vbv[16], v[16];
  ld16(a + base, va);
  ld16(b + base, vbv);
  #pragma unroll
  for (int j = 0; j < 16; ++j) v[j] = gv * va[j] + vbv[j];
  float sum = 0.f, sq = 0.f;
  #pragma unroll
  for (int j = 0; j < 16; ++j) { sum += v[j]; sq += v[j] * v[j]; }
  #pragma unroll
  for (int s = 32; s; s >>= 1) { sum += __shfl_xor(sum, s); sq += __shfl_xor(sq, s); }
  if ((tid & 63) == 0) { red[tid >> 6] = sum; red[4 + (tid >> 6)] = sq; }
  __syncthreads();
  sum = red[0] + red[1] + red[2] + red[3];
  sq  = red[4] + red[5] + red[6] + red[7];
  float mean = sum * (1.f / NPIX);
  float var  = fmaxf(sq * (1.f / NPIX) - mean * mean, 0.f);
  float rstd = rsqrtf(var + 1e-5f);
  float o[16];
  #pragma unroll
  for (int j = 0; j < 16; ++j) o[j] = (v[j] - mean) * rstd;
  st16(out + base, o);
}

// ---- two independent InstanceNorms in one launch (both bf16+float, G=1) ----
__global__ __launch_bounds__(256) void inorm2_k(
    const bf16* __restrict__ a0, const float* __restrict__ b0,
    const float* __restrict__ g0, bf16* __restrict__ o0,
    const bf16* __restrict__ a1, const float* __restrict__ b1,
    const float* __restrict__ g1, bf16* __restrict__ o1)
{
  __shared__ float red[8];
  const int tid = threadIdx.x;
  const int sel = blockIdx.x >> 9;
  const int row = blockIdx.x & 511;
  const bf16* a = sel ? a1 : a0;
  const float* b = sel ? b1 : b0;
  const float* g = sel ? g1 : g0;
  bf16* out = sel ? o1 : o0;
  const long base = (long)row * NPIX + tid * 16;
  float gv = *g;
  float va[16], vbv[16], v[16];
  ld16(a + base, va);
  ld16(b + base, vbv);
  #pragma unroll
  for (int j = 0; j < 16; ++j) v[j] = gv * va[j] + vbv[j];
  float sum = 0.f, sq = 0.f;
  #pragma unroll
  for (int j = 0; j < 16; ++j) { sum += v[j]; sq += v[j] * v[j]; }
  #pragma unroll
  for (int s = 32; s; s >>= 1) { sum += __shfl_xor(sum, s); sq += __shfl_xor(sq, s); }
  if ((tid & 63) == 0) { red[tid >> 6] = sum; red[4 + (tid >> 6)] = sq; }
  __syncthreads();
  sum = red[0] + red[1] + red[2] + red[3];
  sq  = red[4] + red[5] + red[6] + red[7];
  float mean = sum * (1.f / NPIX);
  float var  = fmaxf(sq * (1.f / NPIX) - mean * mean, 0.f);
  float rstd = rsqrtf(var + 1e-5f);
  float o[16];
  #pragma unroll
  for (int j = 0; j < 16; ++j) o[j] = (v[j] - mean) * rstd;
  st16(out + base, o);
}

// ---- fused dependent pair: u4 = inorm(inorm(g*t0 + y) + u3) ----------------
__global__ __launch_bounds__(256) void inorm_pair_k(
    const bf16* __restrict__ t0, const float* __restrict__ y,
    const float* __restrict__ g, const bf16* __restrict__ u3,
    bf16* __restrict__ u4)
{
  __shared__ float red[16];
  const int tid = threadIdx.x;
  const long base = (long)blockIdx.x * NPIX + tid * 16;
  float gv = *g;
  float va[16], vbv[16], v[16];
  ld16(t0 + base, va);
  ld16(y + base, vbv);
  #pragma unroll
  for (int j = 0; j < 16; ++j) v[j] = gv * va[j] + vbv[j];
  float sum = 0.f, sq = 0.f;
  #pragma unroll
  for (int j = 0; j < 16; ++j) { sum += v[j]; sq += v[j] * v[j]; }
  #pragma unroll
  for (int s = 32; s; s >>= 1) { sum += __shfl_xor(sum, s); sq += __shfl_xor(sq, s); }
  if ((tid & 63) == 0) { red[tid >> 6] = sum; red[4 + (tid >> 6)] = sq; }
  __syncthreads();
  sum = red[0] + red[1] + red[2] + red[3];
  sq  = red[4] + red[5] + red[6] + red[7];
  float mean = sum * (1.f / NPIX);
  float var  = fmaxf(sq * (1.f / NPIX) - mean * mean, 0.f);
  float rstd = rsqrtf(var + 1e-5f);
  // second stage: w = o1 + u3, stats again
  float vu[16];
  ld16(u3 + base, vu);
  #pragma unroll
  for (int j = 0; j < 16; ++j) v[j] = (v[j] - mean) * rstd + vu[j];
  sum = 0.f; sq = 0.f;
  #pragma unroll
  for (int j = 0; j < 16; ++j) { sum += v[j]; sq += v[j] * v[j]; }
  #pragma unroll
  for (int s = 32; s; s >>= 1) { sum += __shfl_xor(sum, s); sq += __shfl_xor(sq, s); }
  if ((tid & 63) == 0) { red[8 + (tid >> 6)] = sum; red[12 + (tid >> 6)] = sq; }
  __syncthreads();
  sum = red[8] + red[9] + red[10] + red[11];
  sq  = red[12] + red[13] + red[14] + red[15];
  mean = sum * (1.f / NPIX);
  var  = fmaxf(sq * (1.f / NPIX) - mean * mean, 0.f);
  rstd = rsqrtf(var + 1e-5f);
  float o[16];
  #pragma unroll
  for (int j = 0; j < 16; ++j) o[j] = (v[j] - mean) * rstd;
  st16(u4 + base, o);
}

// ---- host-side helpers ------------------------------------------------------
static const long CN = CNL;

// fused flash attention: CB picked so both launches are 512 blocks (2/CU).
static void attn_core(int nb, bf16* qkv, bf16* qkt, bf16* t0, hipStream_t stream)
{
  if (nb == 4)
    fattn_k<128><<<dim3(64, 2, 4), dim3(512), 0, stream>>>(qkt, qkv + 64 * NPIX, t0);
  else
    fattn_k<64><<<dim3(64, 4, 2), dim3(512), 0, stream>>>(qkt, qkv + 64 * NPIX, t0);
}

static void run_conv(const bf16* src, const bf16* wcvt, const float* cb,
                     bf16* dst, hipStream_t stream)
{
  conv_k<<<dim3(64, 2, 2), dim3(512), 0, stream>>>(src, wcvt, cb, dst);
}

// ---------------------------------------------------------------------------
extern "C" void kernel_launch(void* const* d_in, const int* in_sizes, int n_in,
                              void* d_out, int out_size, void* d_ws, size_t ws_size,
                              hipStream_t stream)
{
  (void)in_sizes; (void)n_in; (void)out_size; (void)ws_size;
  const float* x = (const float*)d_in[0];
  const float* y = (const float*)d_in[1];
  auto W = [&](int i) { return (const float*)d_in[i]; };

  char* wp = (char*)d_ws;
  auto take = [&](size_t nbytes) { char* p = wp; wp += (nbytes + 255) & ~(size_t)255; return p; };
  bf16*  qkv   = (bf16*)take((size_t)4 * QKVSTR * 2);
  bf16*  qkt   = (bf16*)take((size_t)4 * QKTSTR * 2);
  bf16*  t0    = (bf16*)take((size_t)4 * CN * 2);
  bf16*  u1    = (bf16*)take(2 * CN * 2);
  bf16*  u2    = (bf16*)take(2 * CN * 2);
  bf16*  u3    = (bf16*)take(2 * CN * 2);
  bf16*  u4    = (bf16*)take(2 * CN * 2);
  bf16*  wcvt1 = (bf16*)take((size_t)589824 * 2);
  bf16*  wcvt2 = (bf16*)take((size_t)589824 * 2);
  float* wcat1 = (float*)take((size_t)81920 * 4);
  float* bcat1 = (float*)take(320 * 4);
  float* wcat2 = (float*)take((size_t)81920 * 4);
  float* bcat2 = (float*)take(320 * 4);
  float* wqk   = (float*)take((size_t)16384 * 4);
  float* bqk   = (float*)take(64 * 4);
  bf16*  cvout = qkv;                                         // conv out (aliased)

  dim3 TB(256);

  // ---- prep: all weight concat/convert in one launch ----
  prep_k<<<dim3(5315), TB, 0, stream>>>(
      W(23), W(25), wcvt1, wcvt2,
      W(2), W(3), W(4), W(5), W(6), W(7), wcat1, bcat1,
      W(9), W(10), W(11), W(12), W(13), W(14), wcat2, bcat2,
      W(16), W(17), W(18), W(19), wqk, bqk);

  // ---- stages A+B attention together: z = stage*2 + batch ----
  proj_k<1,float><<<dim3(64,5,4), TB, 0, stream>>>(
      wcat1, wcat2, x, y, bcat1, bcat2, qkv, qkt, 320, NPIX, 256, CN, QKVSTR, 8);
  attn_core(4, qkv, qkt, t0, stream);

  // ---- out_1 / out_3 inorms (merged) ----
  inorm2_k<<<dim3(1024), TB, 0, stream>>>(t0, x, W(8), u1,
                                          t0 + 2 * CN, y, W(15), u3);

  // ---- conv1 -> out_2 ----
  run_conv(u1, wcvt1, W(24), cvout, stream);
  inorm_k<bf16,bf16,bf16,0><<<dim3(512), TB, 0, stream>>>(u1, cvout, nullptr, u2);

  // ---- stage C: merged projection (qk from out_2, v from out_3) ----
  projc_k<<<dim3(64, 5, 2), TB, 0, stream>>>(
      wqk, bqk, u2, W(20), W(21), u3, qkv, qkt);
  attn_core(2, qkv, qkt, t0, stream);
  // fused: u4 = inorm(inorm(g*t0 + y) + u3)
  inorm_pair_k<<<dim3(512), TB, 0, stream>>>(t0, y, W(22), u3, u4);
  run_conv(u4, wcvt2, W(26), cvout, stream);
  inorm_k<bf16,bf16,float,0><<<dim3(512), TB, 0, stream>>>(u4, cvout, nullptr, (float*)d_out);
}